// Round 11
// baseline (214.849 us; speedup 1.0000x reference)
//
#include <hip/hip_runtime.h>
#include <cstdint>
#include <cstddef>

#define NEG_SLOPE 0.2f

typedef __bf16 bf16x8 __attribute__((ext_vector_type(8)));
typedef float f32x4 __attribute__((ext_vector_type(4)));

static __device__ __forceinline__ unsigned short f2bf(float f) {
  unsigned int u = __float_as_uint(f);
  unsigned int r = (u + 0x7FFFu + ((u >> 16) & 1u)) >> 16;
  return (unsigned short)r;
}
static __device__ __forceinline__ float bf2f(unsigned short u) {
  return __uint_as_float(((unsigned int)u) << 16);
}
static __device__ __forceinline__ float pklo(unsigned int x) {
  return __uint_as_float(x << 16);
}
static __device__ __forceinline__ float pkhi(unsigned int x) {
  return __uint_as_float(x & 0xffff0000u);
}

// ---------------- CSR build ----------------
__global__ void k_zero_i32(int* __restrict__ p, int n) {
  int i = blockIdx.x * 256 + threadIdx.x;
  if (i < n) p[i] = 0;
}

__global__ void k_degree(const int* __restrict__ ei, int* __restrict__ deg, int E) {
  int e = blockIdx.x * 256 + threadIdx.x;
  if (e < E) atomicAdd(&deg[ei[E + e]], 1);  // ei[E+e] = dst
}

__global__ __launch_bounds__(256) void k_scan_local(const int* __restrict__ deg,
                                                    int* __restrict__ lex,
                                                    int* __restrict__ bsum, int n) {
  __shared__ int ts[256];
  const int t = threadIdx.x;
  const int base = blockIdx.x * 1024 + t * 4;
  int4 d = {0, 0, 0, 0};
  if (base + 3 < n) d = *reinterpret_cast<const int4*>(&deg[base]);
  else {
    if (base + 0 < n) d.x = deg[base + 0];
    if (base + 1 < n) d.y = deg[base + 1];
    if (base + 2 < n) d.z = deg[base + 2];
  }
  int s = d.x + d.y + d.z + d.w;
  ts[t] = s;
  __syncthreads();
  for (int off = 1; off < 256; off <<= 1) {
    int y = (t >= off) ? ts[t - off] : 0;
    __syncthreads();
    ts[t] += y;
    __syncthreads();
  }
  int pre = ts[t] - s;
  int4 o;
  o.x = pre; o.y = pre + d.x; o.z = pre + d.x + d.y; o.w = pre + d.x + d.y + d.z;
  if (base + 3 < n) *reinterpret_cast<int4*>(&lex[base]) = o;
  else {
    if (base + 0 < n) lex[base + 0] = o.x;
    if (base + 1 < n) lex[base + 1] = o.y;
    if (base + 2 < n) lex[base + 2] = o.z;
  }
  if (t == 255) bsum[blockIdx.x] = ts[255];
}

__global__ __launch_bounds__(256) void k_scan_bsum(int* __restrict__ bsum, int nb) {
  __shared__ int ts[256];
  const int t = threadIdx.x;
  int v = (t < nb) ? bsum[t] : 0;
  ts[t] = v;
  __syncthreads();
  for (int off = 1; off < 256; off <<= 1) {
    int y = (t >= off) ? ts[t - off] : 0;
    __syncthreads();
    ts[t] += y;
    __syncthreads();
  }
  if (t < nb) bsum[t] = ts[t] - v;
}

__global__ void k_scan_add(const int* __restrict__ lex, const int* __restrict__ bsum,
                           int* __restrict__ rowptr, int* __restrict__ cursor,
                           int n, int E) {
  int i = blockIdx.x * 256 + threadIdx.x;
  if (i < n) {
    int v = lex[i] + bsum[i >> 10];
    rowptr[i] = v;
    cursor[i] = v;
  }
  if (i == n) rowptr[n] = E;
}

// col is ushort: node ids < 65536 (N = 50000)
__global__ void k_scatter(const int* __restrict__ ei, int* __restrict__ cursor,
                          unsigned short* __restrict__ col, int E) {
  int e = blockIdx.x * 256 + threadIdx.x;
  if (e >= E) return;
  int d = ei[E + e];
  int pos = atomicAdd(&cursor[d], 1);
  col[pos] = (unsigned short)ei[e];
}

// ---------------- weight prep (all layers in one launch) ----------------
static __device__ __forceinline__ unsigned short pack_wt_elem(
    const float* __restrict__ Wl, const float* __restrict__ Ws,
    const float* __restrict__ Wd, const float* __restrict__ as_,
    const float* __restrict__ ad_, int t) {
  int j = t >> 7, k = t & 127;
  float val;
  if (j < 128) val = Wl[k * 128 + j];
  else if (j < 256) val = Ws[k * 128 + (j - 128)];
  else {
    int jj = j - 256;
    int h = jj & 7;
    const float* W = (jj < 8) ? Ws : Wd;
    const float* a = (jj < 8) ? as_ : ad_;
    float s = 0.f;
#pragma unroll
    for (int c = 0; c < 16; ++c) s += W[k * 128 + h * 16 + c] * a[h * 16 + c];
    val = s;
  }
  return f2bf(val);
}

__global__ void k_pack_all(
    const float* __restrict__ Wl0, const float* __restrict__ Ws0, const float* __restrict__ Wd0,
    const float* __restrict__ as0, const float* __restrict__ ad0,
    const float* __restrict__ Wl1, const float* __restrict__ Ws1, const float* __restrict__ Wd1,
    const float* __restrict__ as1, const float* __restrict__ ad1,
    const float* __restrict__ Wo,
    unsigned short* __restrict__ wt0, unsigned short* __restrict__ wt1,
    unsigned short* __restrict__ wot) {
  const int SZ = 272 * 128;
  int t = blockIdx.x * 256 + threadIdx.x;
  if (t < SZ) {
    wt0[t] = pack_wt_elem(Wl0, Ws0, Wd0, as0, ad0, t);
  } else if (t < 2 * SZ) {
    wt1[t - SZ] = pack_wt_elem(Wl1, Ws1, Wd1, as1, ad1, t - SZ);
  } else if (t < 2 * SZ + 64 * 128) {
    int u = t - 2 * SZ;
    int nn = u >> 7, k = u & 127;
    wot[u] = f2bf(Wo[k * 64 + nn]);
  }
}

// ---------------- layer-0 fused MFMA GEMM (x f32 input) ----------------
// 32-row tile, 256 threads = 4 waves = 4 f-slices (wave 3 also owns asd frag).
__global__ __launch_bounds__(256, 3) void k_gemm_fused(
    const float* __restrict__ X, const unsigned short* __restrict__ wt,
    const float* __restrict__ bl, const float* __restrict__ bc,
    unsigned int* __restrict__ ylin_pk, unsigned short* __restrict__ xsb,
    unsigned short* __restrict__ asd_s, unsigned short* __restrict__ asd_d,
    int n) {
  __shared__ __align__(16) unsigned short xa[32][136];
  const int tid = threadIdx.x;
  const int wave = tid >> 6, lane = tid & 63;
  const int lr = lane & 15, lg = lane >> 4;
  const int row0 = blockIdx.x * 32;
  const int f0 = wave * 4;
  const bool w3 = (wave == 3);

  bf16x8 bfr[4][4];
#pragma unroll
  for (int ff = 0; ff < 4; ++ff)
#pragma unroll
    for (int s = 0; s < 4; ++s)
      bfr[ff][s] = *reinterpret_cast<const bf16x8*>(
          &wt[(size_t)((f0 + ff) * 16 + lr) * 128 + s * 32 + lg * 8]);
  bf16x8 bfr4[4];
  if (w3) {
#pragma unroll
    for (int s = 0; s < 4; ++s)
      bfr4[s] = *reinterpret_cast<const bf16x8*>(
          &wt[(size_t)(256 + lr) * 128 + s * 32 + lg * 8]);
  }

#pragma unroll
  for (int i = 0; i < 4; ++i) {
    int c = tid + i * 256;
    int r = c >> 5, kq = c & 31;
    float4 v = make_float4(0.f, 0.f, 0.f, 0.f);
    if (row0 + r < n)
      v = reinterpret_cast<const float4*>(X)[(size_t)(row0 + r) * 32 + kq];
    ushort4 o;
    o.x = f2bf(v.x); o.y = f2bf(v.y); o.z = f2bf(v.z); o.w = f2bf(v.w);
    *reinterpret_cast<ushort4*>(&xa[r][kq * 4]) = o;
  }
  __syncthreads();

  f32x4 acc[2][4];
  f32x4 acc4[2];
#pragma unroll
  for (int g = 0; g < 2; ++g) {
    acc4[g] = (f32x4){0.f, 0.f, 0.f, 0.f};
#pragma unroll
    for (int ff = 0; ff < 4; ++ff) acc[g][ff] = (f32x4){0.f, 0.f, 0.f, 0.f};
  }

#pragma unroll
  for (int s = 0; s < 4; ++s) {
    bf16x8 a0 = *reinterpret_cast<const bf16x8*>(&xa[lr][s * 32 + lg * 8]);
    bf16x8 a1 = *reinterpret_cast<const bf16x8*>(&xa[16 + lr][s * 32 + lg * 8]);
#pragma unroll
    for (int ff = 0; ff < 4; ++ff) {
      acc[0][ff] = __builtin_amdgcn_mfma_f32_16x16x32_bf16(a0, bfr[ff][s], acc[0][ff], 0, 0, 0);
      acc[1][ff] = __builtin_amdgcn_mfma_f32_16x16x32_bf16(a1, bfr[ff][s], acc[1][ff], 0, 0, 0);
    }
    if (w3) {
      acc4[0] = __builtin_amdgcn_mfma_f32_16x16x32_bf16(a0, bfr4[s], acc4[0], 0, 0, 0);
      acc4[1] = __builtin_amdgcn_mfma_f32_16x16x32_bf16(a1, bfr4[s], acc4[1], 0, 0, 0);
    }
  }

  if (f0 < 8) {
#pragma unroll
    for (int g = 0; g < 2; ++g)
#pragma unroll
      for (int ff = 0; ff < 4; ++ff) {
        int j = (f0 + ff) * 16 + lr;
        float blc = bl[j] + bc[j];
#pragma unroll
        for (int r = 0; r < 4; ++r) {
          int row = row0 + g * 16 + lg * 4 + r;
          float vb = acc[g][ff][r] + blc;
          float v2 = __shfl(vb, lane ^ 1);
          if (row < n && (lr & 1) == 0)
            ylin_pk[(size_t)row * 64 + (j >> 1)] =
                (unsigned int)f2bf(vb) | ((unsigned int)f2bf(v2) << 16);
        }
      }
  } else {
#pragma unroll
    for (int g = 0; g < 2; ++g)
#pragma unroll
      for (int ff = 0; ff < 4; ++ff) {
        int j = (f0 - 8 + ff) * 16 + lr;
#pragma unroll
        for (int r = 0; r < 4; ++r) {
          int row = row0 + g * 16 + lg * 4 + r;
          if (row < n) xsb[(size_t)row * 128 + j] = f2bf(acc[g][ff][r]);
        }
      }
    if (w3) {
#pragma unroll
      for (int g = 0; g < 2; ++g)
#pragma unroll
        for (int r = 0; r < 4; ++r) {
          int row = row0 + g * 16 + lg * 4 + r;
          if (row < n) {
            unsigned short v = f2bf(acc4[g][r]);
            if (lr < 8) asd_s[(size_t)row * 8 + lr] = v;
            else        asd_d[(size_t)row * 8 + (lr - 8)] = v;
          }
        }
    }
  }
}

// ---------------- wave-level node aggregation (shared by fused kernels) ------
// One wave aggregates one node. Per 8-edge chunk (branchless):
//   phase1: lane=(el=lane>>3, hh=lane&7): p = exp(leaky(asd_s[col[e]][hh]+asd_d[node][hh]))
//   phase2: lane owns channels (2*lane,2*lane+1); p via ds_bpermute, src via readlane.
// Returns post-ELU h channels (ylin has biases folded).
static __device__ __forceinline__ void wave_aggregate_node(
    int node, int lane,
    const unsigned int* __restrict__ ylin_pk, const unsigned int* __restrict__ xsp,
    const unsigned short* __restrict__ asd_s, const unsigned short* __restrict__ asd_d,
    const int* __restrict__ rowptr, const unsigned short* __restrict__ col,
    float& l0, float& l1) {
  const int el = lane >> 3;
  const int hh = lane & 7;
  const int hb4 = (lane >> 3) << 2;
  const int beg = rowptr[node], end = rowptr[node + 1];
  const float ad_hh = bf2f(asd_d[(size_t)node * 8 + hh]);

  float dsum = 0.f, acc0 = 0.f, acc1 = 0.f;
  for (int ebase = beg; ebase < end; ebase += 8) {
    int e1 = ebase + el;
    bool valid = e1 < end;
    int esafe = valid ? e1 : (end - 1);
    int srcp = (int)__builtin_nontemporal_load(&col[esafe]);
    float sv = bf2f(asd_s[(size_t)srcp * 8 + hh]) + ad_hh;
    sv = fmaxf(sv, NEG_SLOPE * sv);
    float pe = valid ? __expf(sv) : 0.f;
#pragma unroll
    for (int q = 0; q < 8; ++q) {
      float pq = __uint_as_float(__builtin_amdgcn_ds_bpermute(
          q * 32 + hb4, __float_as_uint(pe)));
      int sq = __builtin_amdgcn_readlane(srcp, q * 8);
      unsigned int xv = xsp[(size_t)sq * 64 + lane];
      dsum += pq;
      acc0 += pq * pklo(xv);
      acc1 += pq * pkhi(xv);
    }
  }
  float inv = 1.f / (dsum + 1e-16f);
  unsigned int y = __builtin_nontemporal_load(&ylin_pk[(size_t)node * 64 + lane]);
  l0 = pklo(y) + acc0 * inv;
  l1 = pkhi(y) + acc1 * inv;
  l0 = l0 > 0.f ? l0 : __expf(l0) - 1.f;
  l1 = l1 > 0.f ? l1 : __expf(l1) - 1.f;
}

// ---------------- fused aggregate(L) + GEMM(L+1) ----------------
// 512 threads = 8 waves. Agg: wave w aggregates nodes row0+w*4..+3 into LDS
// (bf16 h rows). GEMM: 17 frags split 2/wave (wave 7 also asd).
__global__ __launch_bounds__(512) void k_agg_gemm(
    const unsigned int* __restrict__ ylin_in, const unsigned int* __restrict__ xsp_in,
    const unsigned short* __restrict__ asds_in, const unsigned short* __restrict__ asdd_in,
    const int* __restrict__ rowptr, const unsigned short* __restrict__ col,
    const unsigned short* __restrict__ wt,
    const float* __restrict__ bl, const float* __restrict__ bc,
    unsigned int* __restrict__ ylin_out, unsigned short* __restrict__ xsb_out,
    unsigned short* __restrict__ asds_out, unsigned short* __restrict__ asdd_out,
    int n) {
  __shared__ __align__(16) unsigned short ha[32][136];
  const int tid = threadIdx.x;
  const int wave = tid >> 6, lane = tid & 63;
  const int lr = lane & 15, lg = lane >> 4;
  const int row0 = blockIdx.x * 32;

  // ---- aggregation phase ----
  unsigned int* hau = reinterpret_cast<unsigned int*>(&ha[0][0]);
#pragma unroll
  for (int i = 0; i < 4; ++i) {
    int nrow = wave * 4 + i;
    int node = row0 + nrow;
    if (node < n) {
      float l0, l1;
      wave_aggregate_node(node, lane, ylin_in, xsp_in, asds_in, asdd_in,
                          rowptr, col, l0, l1);
      hau[nrow * 68 + lane] = (unsigned int)f2bf(l0) | ((unsigned int)f2bf(l1) << 16);
    }
  }
  __builtin_amdgcn_sched_barrier(0);
  __syncthreads();

  // ---- GEMM phase: h(LDS) @ wt -> ylin_out | xsb_out | asd_out ----
  const int f0 = wave * 2;
  const bool w7 = (wave == 7);
  bf16x8 bfr[2][4];
#pragma unroll
  for (int ff = 0; ff < 2; ++ff)
#pragma unroll
    for (int s = 0; s < 4; ++s)
      bfr[ff][s] = *reinterpret_cast<const bf16x8*>(
          &wt[(size_t)((f0 + ff) * 16 + lr) * 128 + s * 32 + lg * 8]);
  bf16x8 bfr4[4];
  if (w7) {
#pragma unroll
    for (int s = 0; s < 4; ++s)
      bfr4[s] = *reinterpret_cast<const bf16x8*>(
          &wt[(size_t)(256 + lr) * 128 + s * 32 + lg * 8]);
  }

  f32x4 acc[2][2];
  f32x4 acc4[2];
#pragma unroll
  for (int g = 0; g < 2; ++g) {
    acc4[g] = (f32x4){0.f, 0.f, 0.f, 0.f};
#pragma unroll
    for (int ff = 0; ff < 2; ++ff) acc[g][ff] = (f32x4){0.f, 0.f, 0.f, 0.f};
  }

#pragma unroll
  for (int s = 0; s < 4; ++s) {
    bf16x8 a0 = *reinterpret_cast<const bf16x8*>(&ha[lr][s * 32 + lg * 8]);
    bf16x8 a1 = *reinterpret_cast<const bf16x8*>(&ha[16 + lr][s * 32 + lg * 8]);
#pragma unroll
    for (int ff = 0; ff < 2; ++ff) {
      acc[0][ff] = __builtin_amdgcn_mfma_f32_16x16x32_bf16(a0, bfr[ff][s], acc[0][ff], 0, 0, 0);
      acc[1][ff] = __builtin_amdgcn_mfma_f32_16x16x32_bf16(a1, bfr[ff][s], acc[1][ff], 0, 0, 0);
    }
    if (w7) {
      acc4[0] = __builtin_amdgcn_mfma_f32_16x16x32_bf16(a0, bfr4[s], acc4[0], 0, 0, 0);
      acc4[1] = __builtin_amdgcn_mfma_f32_16x16x32_bf16(a1, bfr4[s], acc4[1], 0, 0, 0);
    }
  }

#pragma unroll
  for (int g = 0; g < 2; ++g)
#pragma unroll
    for (int ff = 0; ff < 2; ++ff) {
      const int f = f0 + ff;
      if (f < 8) {
        int j = f * 16 + lr;
        float blc = bl[j] + bc[j];
#pragma unroll
        for (int r = 0; r < 4; ++r) {
          int row = row0 + g * 16 + lg * 4 + r;
          float vb = acc[g][ff][r] + blc;
          float v2 = __shfl(vb, lane ^ 1);
          if (row < n && (lr & 1) == 0)
            ylin_out[(size_t)row * 64 + (j >> 1)] =
                (unsigned int)f2bf(vb) | ((unsigned int)f2bf(v2) << 16);
        }
      } else {
        int j = (f - 8) * 16 + lr;
#pragma unroll
        for (int r = 0; r < 4; ++r) {
          int row = row0 + g * 16 + lg * 4 + r;
          if (row < n) xsb_out[(size_t)row * 128 + j] = f2bf(acc[g][ff][r]);
        }
      }
    }
  if (w7) {
#pragma unroll
    for (int g = 0; g < 2; ++g)
#pragma unroll
      for (int r = 0; r < 4; ++r) {
        int row = row0 + g * 16 + lg * 4 + r;
        if (row < n) {
          unsigned short v = f2bf(acc4[g][r]);
          if (lr < 8) asds_out[(size_t)row * 8 + lr] = v;
          else        asdd_out[(size_t)row * 8 + (lr - 8)] = v;
        }
      }
  }
}

// ---------------- fused aggregate(L1) + output projection ----------------
// 512 threads = 8 waves. Agg same as above; GEMM: out[32x64] = h @ wot + b_out.
// Wave w: row-group g=w>>2, col-frag c=w&3.
__global__ __launch_bounds__(512) void k_agg_out(
    const unsigned int* __restrict__ ylin_in, const unsigned int* __restrict__ xsp_in,
    const unsigned short* __restrict__ asds_in, const unsigned short* __restrict__ asdd_in,
    const int* __restrict__ rowptr, const unsigned short* __restrict__ col,
    const unsigned short* __restrict__ wot, const float* __restrict__ bias,
    float* __restrict__ out, int n) {
  __shared__ __align__(16) unsigned short ha[32][136];
  const int tid = threadIdx.x;
  const int wave = tid >> 6, lane = tid & 63;
  const int lr = lane & 15, lg = lane >> 4;
  const int row0 = blockIdx.x * 32;

  unsigned int* hau = reinterpret_cast<unsigned int*>(&ha[0][0]);
#pragma unroll
  for (int i = 0; i < 4; ++i) {
    int nrow = wave * 4 + i;
    int node = row0 + nrow;
    if (node < n) {
      float l0, l1;
      wave_aggregate_node(node, lane, ylin_in, xsp_in, asds_in, asdd_in,
                          rowptr, col, l0, l1);
      hau[nrow * 68 + lane] = (unsigned int)f2bf(l0) | ((unsigned int)f2bf(l1) << 16);
    }
  }
  __builtin_amdgcn_sched_barrier(0);
  __syncthreads();

  const int g = wave >> 2, c = wave & 3;
  bf16x8 bo[4];
#pragma unroll
  for (int s = 0; s < 4; ++s)
    bo[s] = *reinterpret_cast<const bf16x8*>(
        &wot[(size_t)(c * 16 + lr) * 128 + s * 32 + lg * 8]);

  f32x4 acc = (f32x4){0.f, 0.f, 0.f, 0.f};
#pragma unroll
  for (int s = 0; s < 4; ++s) {
    bf16x8 a = *reinterpret_cast<const bf16x8*>(&ha[g * 16 + lr][s * 32 + lg * 8]);
    acc = __builtin_amdgcn_mfma_f32_16x16x32_bf16(a, bo[s], acc, 0, 0, 0);
  }
  float bv = bias[c * 16 + lr];
#pragma unroll
  for (int r = 0; r < 4; ++r) {
    int row = row0 + g * 16 + lg * 4 + r;
    if (row < n) out[(size_t)row * 64 + c * 16 + lr] = acc[r] + bv;
  }
}

// ---------------- launch ----------------
extern "C" void kernel_launch(void* const* d_in, const int* in_sizes, int n_in,
                              void* d_out, int out_size, void* d_ws, size_t ws_size,
                              hipStream_t stream) {
  const float* x      = (const float*)d_in[0];
  const int*   ei     = (const int*)d_in[1];
  const float* W_lin0 = (const float*)d_in[2];
  const float* b_lin0 = (const float*)d_in[3];
  const float* W_src0 = (const float*)d_in[4];
  const float* W_dst0 = (const float*)d_in[5];
  const float* att_s0 = (const float*)d_in[6];
  const float* att_d0 = (const float*)d_in[7];
  const float* b_cnv0 = (const float*)d_in[8];
  const float* W_lin1 = (const float*)d_in[9];
  const float* b_lin1 = (const float*)d_in[10];
  const float* W_src1 = (const float*)d_in[11];
  const float* W_dst1 = (const float*)d_in[12];
  const float* att_s1 = (const float*)d_in[13];
  const float* att_d1 = (const float*)d_in[14];
  const float* b_cnv1 = (const float*)d_in[15];
  const float* W_out  = (const float*)d_in[16];
  const float* b_out  = (const float*)d_in[17];
  float* out = (float*)d_out;

  const int N = in_sizes[0] / 128;
  const int E = in_sizes[1] / 2;
  const int NB = (N + 1023) / 1024;
  const int MB32 = (N + 31) / 32;

  char* p = (char*)d_ws;
  unsigned int* ylin0   = (unsigned int*)p;   p += (size_t)N * 64 * 4;
  unsigned int* ylin1   = (unsigned int*)p;   p += (size_t)N * 64 * 4;
  unsigned short* xsb0  = (unsigned short*)p; p += (size_t)N * 128 * 2;
  unsigned short* xsb1  = (unsigned short*)p; p += (size_t)N * 128 * 2;
  unsigned short* asds0 = (unsigned short*)p; p += (size_t)N * 8 * 2;
  unsigned short* asdd0 = (unsigned short*)p; p += (size_t)N * 8 * 2;
  unsigned short* asds1 = (unsigned short*)p; p += (size_t)N * 8 * 2;
  unsigned short* asdd1 = (unsigned short*)p; p += (size_t)N * 8 * 2;
  unsigned short* wt0   = (unsigned short*)p; p += (size_t)272 * 128 * 2;
  unsigned short* wt1   = (unsigned short*)p; p += (size_t)272 * 128 * 2;
  unsigned short* wot   = (unsigned short*)p; p += (size_t)64 * 128 * 2;
  int* rowptr = (int*)p;                      p += (size_t)(N + 4) * 4;
  int* cursor = (int*)p;                      p += (size_t)N * 4;
  int* deg    = (int*)p;                      p += (size_t)N * 4;
  int* lex    = (int*)p;                      p += (size_t)N * 4;
  int* bsum   = (int*)p;                      p += (size_t)256 * 4;
  unsigned short* col = (unsigned short*)p;   p += (size_t)E * 2;

  dim3 b256(256), b512(512);

  // CSR by dst (shared by both layers)
  k_zero_i32<<<(N + 255) / 256, b256, 0, stream>>>(deg, N);
  k_degree<<<(E + 255) / 256, b256, 0, stream>>>(ei, deg, E);
  k_scan_local<<<NB, b256, 0, stream>>>(deg, lex, bsum, N);
  k_scan_bsum<<<1, b256, 0, stream>>>(bsum, NB);
  k_scan_add<<<(N + 256) / 256, b256, 0, stream>>>(lex, bsum, rowptr, cursor, N, E);
  k_scatter<<<(E + 255) / 256, b256, 0, stream>>>(ei, cursor, col, E);

  // all weight packs in one launch
  k_pack_all<<<(2 * 272 * 128 + 64 * 128 + 255) / 256, b256, 0, stream>>>(
      W_lin0, W_src0, W_dst0, att_s0, att_d0,
      W_lin1, W_src1, W_dst1, att_s1, att_d1,
      W_out, wt0, wt1, wot);

  // layer 0 GEMM: x -> ylin0 | xsb0 | asd0
  k_gemm_fused<<<MB32, b256, 0, stream>>>(x, wt0, b_lin0, b_cnv0,
                                          ylin0, xsb0, asds0, asdd0, N);
  // aggregate(L0) + GEMM(L1): -> ylin1 | xsb1 | asd1  (h lives in LDS only)
  k_agg_gemm<<<MB32, b512, 0, stream>>>(
      ylin0, (const unsigned int*)xsb0, asds0, asdd0, rowptr, col,
      wt1, b_lin1, b_cnv1, ylin1, xsb1, asds1, asdd1, N);
  // aggregate(L1) + output projection -> out
  k_agg_out<<<MB32, b512, 0, stream>>>(
      ylin1, (const unsigned int*)xsb1, asds1, asdd1, rowptr, col,
      wot, b_out, out, N);
}

// Round 12
// 187.145 us; speedup vs baseline: 1.1480x; 1.1480x over previous
//
#include <hip/hip_runtime.h>
#include <cstdint>
#include <cstddef>

#define NEG_SLOPE 0.2f

typedef __bf16 bf16x8 __attribute__((ext_vector_type(8)));
typedef float f32x4 __attribute__((ext_vector_type(4)));

static __device__ __forceinline__ unsigned short f2bf(float f) {
  unsigned int u = __float_as_uint(f);
  unsigned int r = (u + 0x7FFFu + ((u >> 16) & 1u)) >> 16;
  return (unsigned short)r;
}
static __device__ __forceinline__ float bf2f(unsigned short u) {
  return __uint_as_float(((unsigned int)u) << 16);
}
static __device__ __forceinline__ float pklo(unsigned int x) {
  return __uint_as_float(x << 16);
}
static __device__ __forceinline__ float pkhi(unsigned int x) {
  return __uint_as_float(x & 0xffff0000u);
}

// ---------------- CSR build ----------------
__global__ void k_degree(const int* __restrict__ ei, int* __restrict__ deg, int E) {
  int e = blockIdx.x * 256 + threadIdx.x;
  if (e < E) atomicAdd(&deg[ei[E + e]], 1);  // ei[E+e] = dst
}

__global__ __launch_bounds__(256) void k_scan_local(const int* __restrict__ deg,
                                                    int* __restrict__ lex,
                                                    int* __restrict__ bsum, int n) {
  __shared__ int ts[256];
  const int t = threadIdx.x;
  const int base = blockIdx.x * 1024 + t * 4;
  int4 d = {0, 0, 0, 0};
  if (base + 3 < n) d = *reinterpret_cast<const int4*>(&deg[base]);
  else {
    if (base + 0 < n) d.x = deg[base + 0];
    if (base + 1 < n) d.y = deg[base + 1];
    if (base + 2 < n) d.z = deg[base + 2];
  }
  int s = d.x + d.y + d.z + d.w;
  ts[t] = s;
  __syncthreads();
  for (int off = 1; off < 256; off <<= 1) {
    int y = (t >= off) ? ts[t - off] : 0;
    __syncthreads();
    ts[t] += y;
    __syncthreads();
  }
  int pre = ts[t] - s;
  int4 o;
  o.x = pre; o.y = pre + d.x; o.z = pre + d.x + d.y; o.w = pre + d.x + d.y + d.z;
  if (base + 3 < n) *reinterpret_cast<int4*>(&lex[base]) = o;
  else {
    if (base + 0 < n) lex[base + 0] = o.x;
    if (base + 1 < n) lex[base + 1] = o.y;
    if (base + 2 < n) lex[base + 2] = o.z;
  }
  if (t == 255) bsum[blockIdx.x] = ts[255];
}

__global__ __launch_bounds__(256) void k_scan_bsum(int* __restrict__ bsum, int nb) {
  __shared__ int ts[256];
  const int t = threadIdx.x;
  int v = (t < nb) ? bsum[t] : 0;
  ts[t] = v;
  __syncthreads();
  for (int off = 1; off < 256; off <<= 1) {
    int y = (t >= off) ? ts[t - off] : 0;
    __syncthreads();
    ts[t] += y;
    __syncthreads();
  }
  if (t < nb) bsum[t] = ts[t] - v;
}

__global__ void k_scan_add(const int* __restrict__ lex, const int* __restrict__ bsum,
                           int* __restrict__ rowptr, int* __restrict__ cursor,
                           int n, int E) {
  int i = blockIdx.x * 256 + threadIdx.x;
  if (i < n) {
    int v = lex[i] + bsum[i >> 10];
    rowptr[i] = v;
    cursor[i] = v;
  }
  if (i == n) rowptr[n] = E;
}

// col is ushort: node ids < 65536 (N = 50000)
__global__ void k_scatter(const int* __restrict__ ei, int* __restrict__ cursor,
                          unsigned short* __restrict__ col, int E) {
  int e = blockIdx.x * 256 + threadIdx.x;
  if (e >= E) return;
  int d = ei[E + e];
  int pos = atomicAdd(&cursor[d], 1);
  col[pos] = (unsigned short)ei[e];
}

// ---------------- weight prep (all layers in one launch) ----------------
static __device__ __forceinline__ unsigned short pack_wt_elem(
    const float* __restrict__ Wl, const float* __restrict__ Ws,
    const float* __restrict__ Wd, const float* __restrict__ as_,
    const float* __restrict__ ad_, int t) {
  int j = t >> 7, k = t & 127;
  float val;
  if (j < 128) val = Wl[k * 128 + j];
  else if (j < 256) val = Ws[k * 128 + (j - 128)];
  else {
    int jj = j - 256;
    int h = jj & 7;
    const float* W = (jj < 8) ? Ws : Wd;
    const float* a = (jj < 8) ? as_ : ad_;
    float s = 0.f;
#pragma unroll
    for (int c = 0; c < 16; ++c) s += W[k * 128 + h * 16 + c] * a[h * 16 + c];
    val = s;
  }
  return f2bf(val);
}

__global__ void k_pack_all(
    const float* __restrict__ Wl0, const float* __restrict__ Ws0, const float* __restrict__ Wd0,
    const float* __restrict__ as0, const float* __restrict__ ad0,
    const float* __restrict__ Wl1, const float* __restrict__ Ws1, const float* __restrict__ Wd1,
    const float* __restrict__ as1, const float* __restrict__ ad1,
    const float* __restrict__ Wo,
    unsigned short* __restrict__ wt0, unsigned short* __restrict__ wt1,
    unsigned short* __restrict__ wot) {
  const int SZ = 272 * 128;
  int t = blockIdx.x * 256 + threadIdx.x;
  if (t < SZ) {
    wt0[t] = pack_wt_elem(Wl0, Ws0, Wd0, as0, ad0, t);
  } else if (t < 2 * SZ) {
    wt1[t - SZ] = pack_wt_elem(Wl1, Ws1, Wd1, as1, ad1, t - SZ);
  } else if (t < 2 * SZ + 64 * 128) {
    int u = t - 2 * SZ;
    int nn = u >> 7, k = u & 127;
    wot[u] = f2bf(Wo[k * 64 + nn]);
  }
}

// ---------------- fused MFMA GEMM (non-persistent, B in registers) ----------------
// 32-row tile, 256 threads = 4 waves = 4 f-slices (wave 3 also owns asd frag).
// Outputs: ylin_pk[N][64] uint (bf16 pairs, biases folded), xsb[N][128] bf16,
// asd_s/asd_d[N][8] bf16.
template <typename TIN>
__global__ __launch_bounds__(256, 3) void k_gemm_fused(
    const TIN* __restrict__ X, const unsigned short* __restrict__ wt,
    const float* __restrict__ bl, const float* __restrict__ bc,
    unsigned int* __restrict__ ylin_pk, unsigned short* __restrict__ xsb,
    unsigned short* __restrict__ asd_s, unsigned short* __restrict__ asd_d,
    int n) {
  __shared__ __align__(16) unsigned short xa[32][136];
  const int tid = threadIdx.x;
  const int wave = tid >> 6, lane = tid & 63;
  const int lr = lane & 15, lg = lane >> 4;
  const int row0 = blockIdx.x * 32;
  const int f0 = wave * 4;
  const bool w3 = (wave == 3);

  // B fragments from global (L2-hot, identical across blocks)
  bf16x8 bfr[4][4];
#pragma unroll
  for (int ff = 0; ff < 4; ++ff)
#pragma unroll
    for (int s = 0; s < 4; ++s)
      bfr[ff][s] = *reinterpret_cast<const bf16x8*>(
          &wt[(size_t)((f0 + ff) * 16 + lr) * 128 + s * 32 + lg * 8]);
  bf16x8 bfr4[4];
  if (w3) {
#pragma unroll
    for (int s = 0; s < 4; ++s)
      bfr4[s] = *reinterpret_cast<const bf16x8*>(
          &wt[(size_t)(256 + lr) * 128 + s * 32 + lg * 8]);
  }

  // stage X tile (32 rows x 128) into LDS as bf16
  if constexpr (sizeof(TIN) == 4) {
#pragma unroll
    for (int i = 0; i < 4; ++i) {
      int c = tid + i * 256;          // 1024 float4 chunks
      int r = c >> 5, kq = c & 31;
      float4 v = make_float4(0.f, 0.f, 0.f, 0.f);
      if (row0 + r < n)
        v = reinterpret_cast<const float4*>(X)[(size_t)(row0 + r) * 32 + kq];
      ushort4 o;
      o.x = f2bf(v.x); o.y = f2bf(v.y); o.z = f2bf(v.z); o.w = f2bf(v.w);
      *reinterpret_cast<ushort4*>(&xa[r][kq * 4]) = o;
    }
  } else {
#pragma unroll
    for (int i = 0; i < 2; ++i) {
      int c = tid + i * 256;          // 512 uint4 chunks
      int r = c >> 4, ko = c & 15;
      uint4 v = {0u, 0u, 0u, 0u};
      if (row0 + r < n)
        v = reinterpret_cast<const uint4*>(X)[(size_t)(row0 + r) * 16 + ko];
      *reinterpret_cast<uint4*>(&xa[r][ko * 8]) = v;
    }
  }
  __syncthreads();

  f32x4 acc[2][4];
  f32x4 acc4[2];
#pragma unroll
  for (int g = 0; g < 2; ++g) {
    acc4[g] = (f32x4){0.f, 0.f, 0.f, 0.f};
#pragma unroll
    for (int ff = 0; ff < 4; ++ff) acc[g][ff] = (f32x4){0.f, 0.f, 0.f, 0.f};
  }

#pragma unroll
  for (int s = 0; s < 4; ++s) {
    bf16x8 a0 = *reinterpret_cast<const bf16x8*>(&xa[lr][s * 32 + lg * 8]);
    bf16x8 a1 = *reinterpret_cast<const bf16x8*>(&xa[16 + lr][s * 32 + lg * 8]);
#pragma unroll
    for (int ff = 0; ff < 4; ++ff) {
      acc[0][ff] = __builtin_amdgcn_mfma_f32_16x16x32_bf16(a0, bfr[ff][s], acc[0][ff], 0, 0, 0);
      acc[1][ff] = __builtin_amdgcn_mfma_f32_16x16x32_bf16(a1, bfr[ff][s], acc[1][ff], 0, 0, 0);
    }
    if (w3) {
      acc4[0] = __builtin_amdgcn_mfma_f32_16x16x32_bf16(a0, bfr4[s], acc4[0], 0, 0, 0);
      acc4[1] = __builtin_amdgcn_mfma_f32_16x16x32_bf16(a1, bfr4[s], acc4[1], 0, 0, 0);
    }
  }

  if (f0 < 8) {   // ylin region (waves 0-1), packed bf16 pairs, biases folded
#pragma unroll
    for (int g = 0; g < 2; ++g)
#pragma unroll
      for (int ff = 0; ff < 4; ++ff) {
        int j = (f0 + ff) * 16 + lr;
        float blc = bl[j] + bc[j];
#pragma unroll
        for (int r = 0; r < 4; ++r) {
          int row = row0 + g * 16 + lg * 4 + r;
          float vb = acc[g][ff][r] + blc;
          float v2 = __shfl(vb, lane ^ 1);
          if (row < n && (lr & 1) == 0)
            ylin_pk[(size_t)row * 64 + (j >> 1)] =
                (unsigned int)f2bf(vb) | ((unsigned int)f2bf(v2) << 16);
        }
      }
  } else {        // xsb region (waves 2-3)
#pragma unroll
    for (int g = 0; g < 2; ++g)
#pragma unroll
      for (int ff = 0; ff < 4; ++ff) {
        int j = (f0 - 8 + ff) * 16 + lr;
#pragma unroll
        for (int r = 0; r < 4; ++r) {
          int row = row0 + g * 16 + lg * 4 + r;
          if (row < n) xsb[(size_t)row * 128 + j] = f2bf(acc[g][ff][r]);
        }
      }
    if (w3) {
#pragma unroll
      for (int g = 0; g < 2; ++g)
#pragma unroll
        for (int r = 0; r < 4; ++r) {
          int row = row0 + g * 16 + lg * 4 + r;
          if (row < n) {
            unsigned short v = f2bf(acc4[g][r]);
            if (lr < 8) asd_s[(size_t)row * 8 + lr] = v;
            else        asd_d[(size_t)row * 8 + (lr - 8)] = v;
          }
        }
    }
  }
}

// ---------------- final MFMA GEMM: out[N,64] = h@W_out + b (h bf16) ----------------
__global__ __launch_bounds__(256) void k_gemm_out(
    const unsigned short* __restrict__ X, const unsigned short* __restrict__ wo,
    const float* __restrict__ bias, float* __restrict__ out, int n) {
  __shared__ __align__(16) unsigned short xa[64][136];
  __shared__ __align__(16) unsigned short ws[64][136];
  const int tid = threadIdx.x;
  const int row0 = blockIdx.x * 64;

#pragma unroll
  for (int i = 0; i < 4; ++i) {
    int c = tid + i * 256;
    int r = c >> 4, ko = c & 15;
    uint4 v = {0u, 0u, 0u, 0u};
    if (row0 + r < n)
      v = reinterpret_cast<const uint4*>(X)[(size_t)(row0 + r) * 16 + ko];
    *reinterpret_cast<uint4*>(&xa[r][ko * 8]) = v;
  }
#pragma unroll
  for (int i = 0; i < 4; ++i) {
    int c = tid + i * 256;
    int r = c >> 4, ko = c & 15;
    *reinterpret_cast<uint4*>(&ws[r][ko * 8]) =
        reinterpret_cast<const uint4*>(wo)[(size_t)r * 16 + ko];
  }
  __syncthreads();

  const int w = tid >> 6, lane = tid & 63;
  const int lr = lane & 15, lg = lane >> 4;
  f32x4 acc[4];
#pragma unroll
  for (int f = 0; f < 4; ++f) acc[f] = (f32x4){0.f, 0.f, 0.f, 0.f};

#pragma unroll
  for (int s = 0; s < 4; ++s) {
    bf16x8 a = *reinterpret_cast<const bf16x8*>(&xa[w * 16 + lr][s * 32 + lg * 8]);
#pragma unroll
    for (int f = 0; f < 4; ++f) {
      bf16x8 b = *reinterpret_cast<const bf16x8*>(&ws[f * 16 + lr][s * 32 + lg * 8]);
      acc[f] = __builtin_amdgcn_mfma_f32_16x16x32_bf16(a, b, acc[f], 0, 0, 0);
    }
  }
#pragma unroll
  for (int f = 0; f < 4; ++f) {
#pragma unroll
    for (int r = 0; r < 4; ++r) {
      int row = row0 + w * 16 + lg * 4 + r;
      if (row < n)
        out[(size_t)row * 64 + f * 16 + lr] = acc[f][r] + bias[f * 16 + lr];
    }
  }
}

// ---------------- fused segment softmax + aggregation + node update ----------------
// One wave per dst node. 16-edge software-pipelined chunks (two 8-edge
// sub-chunks issued together — doubles gathers in flight; avg degree ~12
// finishes in one iteration). Branchless padding: invalid slots pe=0 +
// clamped address.
//   phase1: lane=(el=lane>>3, hh=lane&7): p = exp(leaky(asd_s[col[e]][hh]+asd_d[node][hh]))
//   phase2: lane owns channels (2*lane, 2*lane+1); p via ds_bpermute, src via readlane.
__global__ __launch_bounds__(256) void k_aggregate(
    const unsigned int* __restrict__ ylin_pk, const unsigned int* __restrict__ xsp,
    const unsigned short* __restrict__ asd_s, const unsigned short* __restrict__ asd_d,
    const int* __restrict__ rowptr, const unsigned short* __restrict__ col,
    unsigned int* __restrict__ hout_pk, int n) {
  int node = (blockIdx.x * blockDim.x + threadIdx.x) >> 6;
  if (node >= n) return;
  const int lane = threadIdx.x & 63;
  const int el = lane >> 3;             // phase1 edge slot
  const int hh = lane & 7;              // phase1 head
  const int hb4 = (lane >> 3) << 2;     // phase2: h*4 bpermute byte base
  const int beg = rowptr[node], end = rowptr[node + 1];

  const float ad_hh = bf2f(asd_d[(size_t)node * 8 + hh]);

  float dsum = 0.f, acc0 = 0.f, acc1 = 0.f;
  int ebase = beg;
  // 16-edge pipelined main loop (chunk A always full, chunk B padded)
  for (; ebase + 8 < end; ebase += 16) {
    int eA = ebase + el;                      // < ebase+8 <= end-1: valid
    int eB = ebase + 8 + el;
    bool vB = eB < end;
    int esB = vB ? eB : (end - 1);
    int srcA = (int)__builtin_nontemporal_load(&col[eA]);
    int srcB = (int)__builtin_nontemporal_load(&col[esB]);
    float svA = bf2f(asd_s[(size_t)srcA * 8 + hh]) + ad_hh;
    float svB = bf2f(asd_s[(size_t)srcB * 8 + hh]) + ad_hh;
    svA = fmaxf(svA, NEG_SLOPE * svA);
    svB = fmaxf(svB, NEG_SLOPE * svB);
    float peA = __expf(svA);
    float peB = vB ? __expf(svB) : 0.f;
#pragma unroll
    for (int q = 0; q < 8; ++q) {
      float pq = __uint_as_float(__builtin_amdgcn_ds_bpermute(
          q * 32 + hb4, __float_as_uint(peA)));
      int sq = __builtin_amdgcn_readlane(srcA, q * 8);
      unsigned int xv = xsp[(size_t)sq * 64 + lane];
      dsum += pq;
      acc0 += pq * pklo(xv);
      acc1 += pq * pkhi(xv);
    }
#pragma unroll
    for (int q = 0; q < 8; ++q) {
      float pq = __uint_as_float(__builtin_amdgcn_ds_bpermute(
          q * 32 + hb4, __float_as_uint(peB)));
      int sq = __builtin_amdgcn_readlane(srcB, q * 8);
      unsigned int xv = xsp[(size_t)sq * 64 + lane];
      dsum += pq;
      acc0 += pq * pklo(xv);
      acc1 += pq * pkhi(xv);
    }
  }
  // remainder (<= 8 edges)
  for (; ebase < end; ebase += 8) {
    int e1 = ebase + el;
    bool valid = e1 < end;
    int esafe = valid ? e1 : (end - 1);
    int srcp = (int)__builtin_nontemporal_load(&col[esafe]);
    float sv = bf2f(asd_s[(size_t)srcp * 8 + hh]) + ad_hh;
    sv = fmaxf(sv, NEG_SLOPE * sv);
    float pe = valid ? __expf(sv) : 0.f;
#pragma unroll
    for (int q = 0; q < 8; ++q) {
      float pq = __uint_as_float(__builtin_amdgcn_ds_bpermute(
          q * 32 + hb4, __float_as_uint(pe)));
      int sq = __builtin_amdgcn_readlane(srcp, q * 8);
      unsigned int xv = xsp[(size_t)sq * 64 + lane];
      dsum += pq;
      acc0 += pq * pklo(xv);
      acc1 += pq * pkhi(xv);
    }
  }
  float inv = 1.f / (dsum + 1e-16f);
  unsigned int y = __builtin_nontemporal_load(&ylin_pk[(size_t)node * 64 + lane]);
  float l0 = pklo(y) + acc0 * inv;
  float l1 = pkhi(y) + acc1 * inv;
  l0 = l0 > 0.f ? l0 : __expf(l0) - 1.f;
  l1 = l1 > 0.f ? l1 : __expf(l1) - 1.f;
  hout_pk[(size_t)node * 64 + lane] =
      (unsigned int)f2bf(l0) | ((unsigned int)f2bf(l1) << 16);
}

// ---------------- launch ----------------
extern "C" void kernel_launch(void* const* d_in, const int* in_sizes, int n_in,
                              void* d_out, int out_size, void* d_ws, size_t ws_size,
                              hipStream_t stream) {
  const float* x      = (const float*)d_in[0];
  const int*   ei     = (const int*)d_in[1];
  const float* W_lin0 = (const float*)d_in[2];
  const float* b_lin0 = (const float*)d_in[3];
  const float* W_src0 = (const float*)d_in[4];
  const float* W_dst0 = (const float*)d_in[5];
  const float* att_s0 = (const float*)d_in[6];
  const float* att_d0 = (const float*)d_in[7];
  const float* b_cnv0 = (const float*)d_in[8];
  const float* W_lin1 = (const float*)d_in[9];
  const float* b_lin1 = (const float*)d_in[10];
  const float* W_src1 = (const float*)d_in[11];
  const float* W_dst1 = (const float*)d_in[12];
  const float* att_s1 = (const float*)d_in[13];
  const float* att_d1 = (const float*)d_in[14];
  const float* b_cnv1 = (const float*)d_in[15];
  const float* W_out  = (const float*)d_in[16];
  const float* b_out  = (const float*)d_in[17];
  float* out = (float*)d_out;

  const int N = in_sizes[0] / 128;
  const int E = in_sizes[1] / 2;
  const int NB = (N + 1023) / 1024;
  const int MB32 = (N + 31) / 32;

  char* p = (char*)d_ws;
  unsigned int* ylin    = (unsigned int*)p;   p += (size_t)N * 64 * 4;
  unsigned short* xsb   = (unsigned short*)p; p += (size_t)N * 128 * 2;
  unsigned short* hb    = (unsigned short*)p; p += (size_t)N * 128 * 2;
  unsigned short* asd_s = (unsigned short*)p; p += (size_t)N * 8 * 2;
  unsigned short* asd_d = (unsigned short*)p; p += (size_t)N * 8 * 2;
  unsigned short* wt0   = (unsigned short*)p; p += (size_t)272 * 128 * 2;
  unsigned short* wt1   = (unsigned short*)p; p += (size_t)272 * 128 * 2;
  unsigned short* wot   = (unsigned short*)p; p += (size_t)64 * 128 * 2;
  int* rowptr = (int*)p;                      p += (size_t)(N + 4) * 4;
  int* cursor = (int*)p;                      p += (size_t)N * 4;
  int* deg    = (int*)p;                      p += (size_t)N * 4;
  int* lex    = (int*)p;                      p += (size_t)N * 4;
  int* bsum   = (int*)p;                      p += (size_t)256 * 4;
  unsigned short* col = (unsigned short*)p;   p += (size_t)E * 2;

  dim3 b256(256);

  // CSR by dst (shared by both layers)
  hipMemsetAsync(deg, 0, (size_t)N * 4, stream);
  k_degree<<<(E + 255) / 256, b256, 0, stream>>>(ei, deg, E);
  k_scan_local<<<NB, b256, 0, stream>>>(deg, lex, bsum, N);
  k_scan_bsum<<<1, b256, 0, stream>>>(bsum, NB);
  k_scan_add<<<(N + 256) / 256, b256, 0, stream>>>(lex, bsum, rowptr, cursor, N, E);
  k_scatter<<<(E + 255) / 256, b256, 0, stream>>>(ei, cursor, col, E);

  // all weight packs in one launch
  k_pack_all<<<(2 * 272 * 128 + 64 * 128 + 255) / 256, b256, 0, stream>>>(
      W_lin0, W_src0, W_dst0, att_s0, att_d0,
      W_lin1, W_src1, W_dst1, att_s1, att_d1,
      W_out, wt0, wt1, wot);

  for (int layer = 0; layer < 2; ++layer) {
    const float* bl = layer ? b_lin1 : b_lin0;
    const float* bc = layer ? b_cnv1 : b_cnv0;
    const unsigned short* wt = layer ? wt1 : wt0;

    if (layer == 0)
      k_gemm_fused<float><<<MB32, b256, 0, stream>>>(x, wt0, bl, bc, ylin, xsb,
                                                     asd_s, asd_d, N);
    else
      k_gemm_fused<unsigned short><<<MB32, b256, 0, stream>>>(hb, wt, bl, bc, ylin, xsb,
                                                              asd_s, asd_d, N);
    k_aggregate<<<(N + 3) / 4, b256, 0, stream>>>(
        ylin, (const unsigned int*)xsb, asd_s, asd_d, rowptr, col,
        (unsigned int*)hb, N);
  }
  k_gemm_out<<<(N + 63) / 64, b256, 0, stream>>>(hb, wot, b_out, out, N);
}

// Round 13
// 165.302 us; speedup vs baseline: 1.2997x; 1.1321x over previous
//
#include <hip/hip_runtime.h>
#include <cstdint>
#include <cstddef>

#define NEG_SLOPE 0.2f

typedef __bf16 bf16x8 __attribute__((ext_vector_type(8)));
typedef float f32x4 __attribute__((ext_vector_type(4)));

static __device__ __forceinline__ unsigned short f2bf(float f) {
  unsigned int u = __float_as_uint(f);
  unsigned int r = (u + 0x7FFFu + ((u >> 16) & 1u)) >> 16;
  return (unsigned short)r;
}
static __device__ __forceinline__ float bf2f(unsigned short u) {
  return __uint_as_float(((unsigned int)u) << 16);
}
static __device__ __forceinline__ float pklo(unsigned int x) {
  return __uint_as_float(x << 16);
}
static __device__ __forceinline__ float pkhi(unsigned int x) {
  return __uint_as_float(x & 0xffff0000u);
}

// ---------------- CSR scan ----------------
__global__ __launch_bounds__(256) void k_scan_local(const int* __restrict__ deg,
                                                    int* __restrict__ lex,
                                                    int* __restrict__ bsum, int n) {
  __shared__ int ts[256];
  const int t = threadIdx.x;
  const int base = blockIdx.x * 1024 + t * 4;
  int4 d = {0, 0, 0, 0};
  if (base + 3 < n) d = *reinterpret_cast<const int4*>(&deg[base]);
  else {
    if (base + 0 < n) d.x = deg[base + 0];
    if (base + 1 < n) d.y = deg[base + 1];
    if (base + 2 < n) d.z = deg[base + 2];
  }
  int s = d.x + d.y + d.z + d.w;
  ts[t] = s;
  __syncthreads();
  for (int off = 1; off < 256; off <<= 1) {
    int y = (t >= off) ? ts[t - off] : 0;
    __syncthreads();
    ts[t] += y;
    __syncthreads();
  }
  int pre = ts[t] - s;
  int4 o;
  o.x = pre; o.y = pre + d.x; o.z = pre + d.x + d.y; o.w = pre + d.x + d.y + d.z;
  if (base + 3 < n) *reinterpret_cast<int4*>(&lex[base]) = o;
  else {
    if (base + 0 < n) lex[base + 0] = o.x;
    if (base + 1 < n) lex[base + 1] = o.y;
    if (base + 2 < n) lex[base + 2] = o.z;
  }
  if (t == 255) bsum[blockIdx.x] = ts[255];
}

__global__ __launch_bounds__(256) void k_scan_bsum(int* __restrict__ bsum, int nb) {
  __shared__ int ts[256];
  const int t = threadIdx.x;
  int v = (t < nb) ? bsum[t] : 0;
  ts[t] = v;
  __syncthreads();
  for (int off = 1; off < 256; off <<= 1) {
    int y = (t >= off) ? ts[t - off] : 0;
    __syncthreads();
    ts[t] += y;
    __syncthreads();
  }
  if (t < nb) bsum[t] = ts[t] - v;
}

__global__ void k_scan_add(const int* __restrict__ lex, const int* __restrict__ bsum,
                           int* __restrict__ rowptr, int* __restrict__ cursor,
                           int n, int E) {
  int i = blockIdx.x * 256 + threadIdx.x;
  if (i < n) {
    int v = lex[i] + bsum[i >> 10];
    rowptr[i] = v;
    cursor[i] = v;
  }
  if (i == n) rowptr[n] = E;
}

// ---------------- k_init: weight pack (blocks < packBlocks) + degree count ----
static __device__ __forceinline__ unsigned short pack_wt_elem(
    const float* __restrict__ Wl, const float* __restrict__ Ws,
    const float* __restrict__ Wd, const float* __restrict__ as_,
    const float* __restrict__ ad_, int t) {
  int j = t >> 7, k = t & 127;
  float val;
  if (j < 128) val = Wl[k * 128 + j];
  else if (j < 256) val = Ws[k * 128 + (j - 128)];
  else {
    int jj = j - 256;
    int h = jj & 7;
    const float* W = (jj < 8) ? Ws : Wd;
    const float* a = (jj < 8) ? as_ : ad_;
    float s = 0.f;
#pragma unroll
    for (int c = 0; c < 16; ++c) s += W[k * 128 + h * 16 + c] * a[h * 16 + c];
    val = s;
  }
  return f2bf(val);
}

__global__ void k_init(
    const float* __restrict__ Wl0, const float* __restrict__ Ws0, const float* __restrict__ Wd0,
    const float* __restrict__ as0, const float* __restrict__ ad0,
    const float* __restrict__ Wl1, const float* __restrict__ Ws1, const float* __restrict__ Wd1,
    const float* __restrict__ as1, const float* __restrict__ ad1,
    const float* __restrict__ Wo,
    unsigned short* __restrict__ wt0, unsigned short* __restrict__ wt1,
    unsigned short* __restrict__ wot,
    const int* __restrict__ ei, int* __restrict__ deg, int E, int packBlocks) {
  const int SZ = 272 * 128;
  if ((int)blockIdx.x < packBlocks) {
    int t = blockIdx.x * 256 + threadIdx.x;
    if (t < SZ) {
      wt0[t] = pack_wt_elem(Wl0, Ws0, Wd0, as0, ad0, t);
    } else if (t < 2 * SZ) {
      wt1[t - SZ] = pack_wt_elem(Wl1, Ws1, Wd1, as1, ad1, t - SZ);
    } else if (t < 2 * SZ + 64 * 128) {
      int u = t - 2 * SZ;
      int nn = u >> 7, k = u & 127;
      wot[u] = f2bf(Wo[k * 64 + nn]);
    }
  } else {
    int e = (blockIdx.x - packBlocks) * 256 + threadIdx.x;
    if (e < E) atomicAdd(&deg[ei[E + e]], 1);  // ei[E+e] = dst
  }
}

// ---------------- k_gemm0_scatter: layer-0 GEMM ∪ CSR scatter (interleaved) ---
// Bresenham split over gemmBlocks : scatterBlocks so both kinds co-reside.
// GEMM part: 32-row tile, 4 waves = 4 f-slices (wave 3 also asd frag).
__global__ __launch_bounds__(256, 3) void k_gemm0_scatter(
    const float* __restrict__ X, const unsigned short* __restrict__ wt,
    const float* __restrict__ bl, const float* __restrict__ bc,
    unsigned int* __restrict__ ylin_pk, unsigned short* __restrict__ xsb,
    unsigned short* __restrict__ asd_s, unsigned short* __restrict__ asd_d,
    int n, int gemmBlocks,
    const int* __restrict__ ei, int* __restrict__ cursor,
    unsigned short* __restrict__ col, int E, int total) {
  __shared__ __align__(16) unsigned short xa[32][136];
  const int i = blockIdx.x;
  const int before = (int)(((long long)i * gemmBlocks) / total);
  const int after  = (int)(((long long)(i + 1) * gemmBlocks) / total);

  if (after == before) {           // ---- scatter block ----
    int e = (i - after) * 256 + threadIdx.x;
    if (e < E) {
      int d = ei[E + e];
      int pos = atomicAdd(&cursor[d], 1);
      col[pos] = (unsigned short)ei[e];
    }
    return;
  }

  // ---- gemm block (tile index = before) ----
  const int tid = threadIdx.x;
  const int wave = tid >> 6, lane = tid & 63;
  const int lr = lane & 15, lg = lane >> 4;
  const int row0 = before * 32;
  const int f0 = wave * 4;
  const bool w3 = (wave == 3);

  bf16x8 bfr[4][4];
#pragma unroll
  for (int ff = 0; ff < 4; ++ff)
#pragma unroll
    for (int s = 0; s < 4; ++s)
      bfr[ff][s] = *reinterpret_cast<const bf16x8*>(
          &wt[(size_t)((f0 + ff) * 16 + lr) * 128 + s * 32 + lg * 8]);
  bf16x8 bfr4[4];
  if (w3) {
#pragma unroll
    for (int s = 0; s < 4; ++s)
      bfr4[s] = *reinterpret_cast<const bf16x8*>(
          &wt[(size_t)(256 + lr) * 128 + s * 32 + lg * 8]);
  }

#pragma unroll
  for (int ii = 0; ii < 4; ++ii) {
    int c = tid + ii * 256;
    int r = c >> 5, kq = c & 31;
    float4 v = make_float4(0.f, 0.f, 0.f, 0.f);
    if (row0 + r < n)
      v = reinterpret_cast<const float4*>(X)[(size_t)(row0 + r) * 32 + kq];
    ushort4 o;
    o.x = f2bf(v.x); o.y = f2bf(v.y); o.z = f2bf(v.z); o.w = f2bf(v.w);
    *reinterpret_cast<ushort4*>(&xa[r][kq * 4]) = o;
  }
  __syncthreads();

  f32x4 acc[2][4];
  f32x4 acc4[2];
#pragma unroll
  for (int g = 0; g < 2; ++g) {
    acc4[g] = (f32x4){0.f, 0.f, 0.f, 0.f};
#pragma unroll
    for (int ff = 0; ff < 4; ++ff) acc[g][ff] = (f32x4){0.f, 0.f, 0.f, 0.f};
  }

#pragma unroll
  for (int s = 0; s < 4; ++s) {
    bf16x8 a0 = *reinterpret_cast<const bf16x8*>(&xa[lr][s * 32 + lg * 8]);
    bf16x8 a1 = *reinterpret_cast<const bf16x8*>(&xa[16 + lr][s * 32 + lg * 8]);
#pragma unroll
    for (int ff = 0; ff < 4; ++ff) {
      acc[0][ff] = __builtin_amdgcn_mfma_f32_16x16x32_bf16(a0, bfr[ff][s], acc[0][ff], 0, 0, 0);
      acc[1][ff] = __builtin_amdgcn_mfma_f32_16x16x32_bf16(a1, bfr[ff][s], acc[1][ff], 0, 0, 0);
    }
    if (w3) {
      acc4[0] = __builtin_amdgcn_mfma_f32_16x16x32_bf16(a0, bfr4[s], acc4[0], 0, 0, 0);
      acc4[1] = __builtin_amdgcn_mfma_f32_16x16x32_bf16(a1, bfr4[s], acc4[1], 0, 0, 0);
    }
  }

  if (f0 < 8) {
#pragma unroll
    for (int g = 0; g < 2; ++g)
#pragma unroll
      for (int ff = 0; ff < 4; ++ff) {
        int j = (f0 + ff) * 16 + lr;
        float blc = bl[j] + bc[j];
#pragma unroll
        for (int r = 0; r < 4; ++r) {
          int row = row0 + g * 16 + lg * 4 + r;
          float vb = acc[g][ff][r] + blc;
          float v2 = __shfl(vb, lane ^ 1);
          if (row < n && (lr & 1) == 0)
            ylin_pk[(size_t)row * 64 + (j >> 1)] =
                (unsigned int)f2bf(vb) | ((unsigned int)f2bf(v2) << 16);
        }
      }
  } else {
#pragma unroll
    for (int g = 0; g < 2; ++g)
#pragma unroll
      for (int ff = 0; ff < 4; ++ff) {
        int j = (f0 - 8 + ff) * 16 + lr;
#pragma unroll
        for (int r = 0; r < 4; ++r) {
          int row = row0 + g * 16 + lg * 4 + r;
          if (row < n) xsb[(size_t)row * 128 + j] = f2bf(acc[g][ff][r]);
        }
      }
    if (w3) {
#pragma unroll
      for (int g = 0; g < 2; ++g)
#pragma unroll
        for (int r = 0; r < 4; ++r) {
          int row = row0 + g * 16 + lg * 4 + r;
          if (row < n) {
            unsigned short v = f2bf(acc4[g][r]);
            if (lr < 8) asd_s[(size_t)row * 8 + lr] = v;
            else        asd_d[(size_t)row * 8 + (lr - 8)] = v;
          }
        }
    }
  }
}

// ---------------- layer-1 fused MFMA GEMM (bf16 input, B in registers) --------
__global__ __launch_bounds__(256, 3) void k_gemm_fused1(
    const unsigned short* __restrict__ X, const unsigned short* __restrict__ wt,
    const float* __restrict__ bl, const float* __restrict__ bc,
    unsigned int* __restrict__ ylin_pk, unsigned short* __restrict__ xsb,
    unsigned short* __restrict__ asd_s, unsigned short* __restrict__ asd_d,
    int n) {
  __shared__ __align__(16) unsigned short xa[32][136];
  const int tid = threadIdx.x;
  const int wave = tid >> 6, lane = tid & 63;
  const int lr = lane & 15, lg = lane >> 4;
  const int row0 = blockIdx.x * 32;
  const int f0 = wave * 4;
  const bool w3 = (wave == 3);

  bf16x8 bfr[4][4];
#pragma unroll
  for (int ff = 0; ff < 4; ++ff)
#pragma unroll
    for (int s = 0; s < 4; ++s)
      bfr[ff][s] = *reinterpret_cast<const bf16x8*>(
          &wt[(size_t)((f0 + ff) * 16 + lr) * 128 + s * 32 + lg * 8]);
  bf16x8 bfr4[4];
  if (w3) {
#pragma unroll
    for (int s = 0; s < 4; ++s)
      bfr4[s] = *reinterpret_cast<const bf16x8*>(
          &wt[(size_t)(256 + lr) * 128 + s * 32 + lg * 8]);
  }

#pragma unroll
  for (int i = 0; i < 2; ++i) {
    int c = tid + i * 256;
    int r = c >> 4, ko = c & 15;
    uint4 v = {0u, 0u, 0u, 0u};
    if (row0 + r < n)
      v = reinterpret_cast<const uint4*>(X)[(size_t)(row0 + r) * 16 + ko];
    *reinterpret_cast<uint4*>(&xa[r][ko * 8]) = v;
  }
  __syncthreads();

  f32x4 acc[2][4];
  f32x4 acc4[2];
#pragma unroll
  for (int g = 0; g < 2; ++g) {
    acc4[g] = (f32x4){0.f, 0.f, 0.f, 0.f};
#pragma unroll
    for (int ff = 0; ff < 4; ++ff) acc[g][ff] = (f32x4){0.f, 0.f, 0.f, 0.f};
  }

#pragma unroll
  for (int s = 0; s < 4; ++s) {
    bf16x8 a0 = *reinterpret_cast<const bf16x8*>(&xa[lr][s * 32 + lg * 8]);
    bf16x8 a1 = *reinterpret_cast<const bf16x8*>(&xa[16 + lr][s * 32 + lg * 8]);
#pragma unroll
    for (int ff = 0; ff < 4; ++ff) {
      acc[0][ff] = __builtin_amdgcn_mfma_f32_16x16x32_bf16(a0, bfr[ff][s], acc[0][ff], 0, 0, 0);
      acc[1][ff] = __builtin_amdgcn_mfma_f32_16x16x32_bf16(a1, bfr[ff][s], acc[1][ff], 0, 0, 0);
    }
    if (w3) {
      acc4[0] = __builtin_amdgcn_mfma_f32_16x16x32_bf16(a0, bfr4[s], acc4[0], 0, 0, 0);
      acc4[1] = __builtin_amdgcn_mfma_f32_16x16x32_bf16(a1, bfr4[s], acc4[1], 0, 0, 0);
    }
  }

  if (f0 < 8) {
#pragma unroll
    for (int g = 0; g < 2; ++g)
#pragma unroll
      for (int ff = 0; ff < 4; ++ff) {
        int j = (f0 + ff) * 16 + lr;
        float blc = bl[j] + bc[j];
#pragma unroll
        for (int r = 0; r < 4; ++r) {
          int row = row0 + g * 16 + lg * 4 + r;
          float vb = acc[g][ff][r] + blc;
          float v2 = __shfl(vb, lane ^ 1);
          if (row < n && (lr & 1) == 0)
            ylin_pk[(size_t)row * 64 + (j >> 1)] =
                (unsigned int)f2bf(vb) | ((unsigned int)f2bf(v2) << 16);
        }
      }
  } else {
#pragma unroll
    for (int g = 0; g < 2; ++g)
#pragma unroll
      for (int ff = 0; ff < 4; ++ff) {
        int j = (f0 - 8 + ff) * 16 + lr;
#pragma unroll
        for (int r = 0; r < 4; ++r) {
          int row = row0 + g * 16 + lg * 4 + r;
          if (row < n) xsb[(size_t)row * 128 + j] = f2bf(acc[g][ff][r]);
        }
      }
    if (w3) {
#pragma unroll
      for (int g = 0; g < 2; ++g)
#pragma unroll
        for (int r = 0; r < 4; ++r) {
          int row = row0 + g * 16 + lg * 4 + r;
          if (row < n) {
            unsigned short v = f2bf(acc4[g][r]);
            if (lr < 8) asd_s[(size_t)row * 8 + lr] = v;
            else        asd_d[(size_t)row * 8 + (lr - 8)] = v;
          }
        }
    }
  }
}

// ---------------- final GEMM: out[N,64] = h@W_out + b (B in registers) --------
__global__ __launch_bounds__(256, 3) void k_gemm_out(
    const unsigned short* __restrict__ X, const unsigned short* __restrict__ wot,
    const float* __restrict__ bias, float* __restrict__ out, int n) {
  __shared__ __align__(16) unsigned short xa[32][136];
  const int tid = threadIdx.x;
  const int wave = tid >> 6, lane = tid & 63;
  const int lr = lane & 15, lg = lane >> 4;
  const int row0 = blockIdx.x * 32;

  bf16x8 bo[4];
#pragma unroll
  for (int s = 0; s < 4; ++s)
    bo[s] = *reinterpret_cast<const bf16x8*>(
        &wot[(size_t)(wave * 16 + lr) * 128 + s * 32 + lg * 8]);

#pragma unroll
  for (int i = 0; i < 2; ++i) {
    int c = tid + i * 256;
    int r = c >> 4, ko = c & 15;
    uint4 v = {0u, 0u, 0u, 0u};
    if (row0 + r < n)
      v = reinterpret_cast<const uint4*>(X)[(size_t)(row0 + r) * 16 + ko];
    *reinterpret_cast<uint4*>(&xa[r][ko * 8]) = v;
  }
  __syncthreads();

  f32x4 acc[2];
  acc[0] = (f32x4){0.f, 0.f, 0.f, 0.f};
  acc[1] = (f32x4){0.f, 0.f, 0.f, 0.f};
#pragma unroll
  for (int s = 0; s < 4; ++s) {
    bf16x8 a0 = *reinterpret_cast<const bf16x8*>(&xa[lr][s * 32 + lg * 8]);
    bf16x8 a1 = *reinterpret_cast<const bf16x8*>(&xa[16 + lr][s * 32 + lg * 8]);
    acc[0] = __builtin_amdgcn_mfma_f32_16x16x32_bf16(a0, bo[s], acc[0], 0, 0, 0);
    acc[1] = __builtin_amdgcn_mfma_f32_16x16x32_bf16(a1, bo[s], acc[1], 0, 0, 0);
  }
  float bv = bias[wave * 16 + lr];
#pragma unroll
  for (int g = 0; g < 2; ++g)
#pragma unroll
    for (int r = 0; r < 4; ++r) {
      int row = row0 + g * 16 + lg * 4 + r;
      if (row < n) out[(size_t)row * 64 + wave * 16 + lr] = acc[g][r] + bv;
    }
}

// ---------------- fused segment softmax + aggregation + node update ----------
// One wave per dst node. 16-edge software-pipelined chunks; branchless padding.
__global__ __launch_bounds__(256) void k_aggregate(
    const unsigned int* __restrict__ ylin_pk, const unsigned int* __restrict__ xsp,
    const unsigned short* __restrict__ asd_s, const unsigned short* __restrict__ asd_d,
    const int* __restrict__ rowptr, const unsigned short* __restrict__ col,
    unsigned int* __restrict__ hout_pk, int n) {
  int node = (blockIdx.x * blockDim.x + threadIdx.x) >> 6;
  if (node >= n) return;
  const int lane = threadIdx.x & 63;
  const int el = lane >> 3;
  const int hh = lane & 7;
  const int hb4 = (lane >> 3) << 2;
  const int beg = rowptr[node], end = rowptr[node + 1];

  const float ad_hh = bf2f(asd_d[(size_t)node * 8 + hh]);
  // hoisted: issue ylin load early, ~900-cycle latency hides under gathers
  unsigned int y = __builtin_nontemporal_load(&ylin_pk[(size_t)node * 64 + lane]);

  float dsum = 0.f, acc0 = 0.f, acc1 = 0.f;
  int ebase = beg;
  for (; ebase + 8 < end; ebase += 16) {
    int eA = ebase + el;
    int eB = ebase + 8 + el;
    bool vB = eB < end;
    int esB = vB ? eB : (end - 1);
    int srcA = (int)__builtin_nontemporal_load(&col[eA]);
    int srcB = (int)__builtin_nontemporal_load(&col[esB]);
    float svA = bf2f(asd_s[(size_t)srcA * 8 + hh]) + ad_hh;
    float svB = bf2f(asd_s[(size_t)srcB * 8 + hh]) + ad_hh;
    svA = fmaxf(svA, NEG_SLOPE * svA);
    svB = fmaxf(svB, NEG_SLOPE * svB);
    float peA = __expf(svA);
    float peB = vB ? __expf(svB) : 0.f;
#pragma unroll
    for (int q = 0; q < 8; ++q) {
      float pq = __uint_as_float(__builtin_amdgcn_ds_bpermute(
          q * 32 + hb4, __float_as_uint(peA)));
      int sq = __builtin_amdgcn_readlane(srcA, q * 8);
      unsigned int xv = xsp[(size_t)sq * 64 + lane];
      dsum += pq;
      acc0 += pq * pklo(xv);
      acc1 += pq * pkhi(xv);
    }
#pragma unroll
    for (int q = 0; q < 8; ++q) {
      float pq = __uint_as_float(__builtin_amdgcn_ds_bpermute(
          q * 32 + hb4, __float_as_uint(peB)));
      int sq = __builtin_amdgcn_readlane(srcB, q * 8);
      unsigned int xv = xsp[(size_t)sq * 64 + lane];
      dsum += pq;
      acc0 += pq * pklo(xv);
      acc1 += pq * pkhi(xv);
    }
  }
  for (; ebase < end; ebase += 8) {
    int e1 = ebase + el;
    bool valid = e1 < end;
    int esafe = valid ? e1 : (end - 1);
    int srcp = (int)__builtin_nontemporal_load(&col[esafe]);
    float sv = bf2f(asd_s[(size_t)srcp * 8 + hh]) + ad_hh;
    sv = fmaxf(sv, NEG_SLOPE * sv);
    float pe = valid ? __expf(sv) : 0.f;
#pragma unroll
    for (int q = 0; q < 8; ++q) {
      float pq = __uint_as_float(__builtin_amdgcn_ds_bpermute(
          q * 32 + hb4, __float_as_uint(pe)));
      int sq = __builtin_amdgcn_readlane(srcp, q * 8);
      unsigned int xv = xsp[(size_t)sq * 64 + lane];
      dsum += pq;
      acc0 += pq * pklo(xv);
      acc1 += pq * pkhi(xv);
    }
  }
  float inv = 1.f / (dsum + 1e-16f);
  float l0 = pklo(y) + acc0 * inv;
  float l1 = pkhi(y) + acc1 * inv;
  l0 = l0 > 0.f ? l0 : __expf(l0) - 1.f;
  l1 = l1 > 0.f ? l1 : __expf(l1) - 1.f;
  hout_pk[(size_t)node * 64 + lane] =
      (unsigned int)f2bf(l0) | ((unsigned int)f2bf(l1) << 16);
}

// ---------------- launch ----------------
extern "C" void kernel_launch(void* const* d_in, const int* in_sizes, int n_in,
                              void* d_out, int out_size, void* d_ws, size_t ws_size,
                              hipStream_t stream) {
  const float* x      = (const float*)d_in[0];
  const int*   ei     = (const int*)d_in[1];
  const float* W_lin0 = (const float*)d_in[2];
  const float* b_lin0 = (const float*)d_in[3];
  const float* W_src0 = (const float*)d_in[4];
  const float* W_dst0 = (const float*)d_in[5];
  const float* att_s0 = (const float*)d_in[6];
  const float* att_d0 = (const float*)d_in[7];
  const float* b_cnv0 = (const float*)d_in[8];
  const float* W_lin1 = (const float*)d_in[9];
  const float* b_lin1 = (const float*)d_in[10];
  const float* W_src1 = (const float*)d_in[11];
  const float* W_dst1 = (const float*)d_in[12];
  const float* att_s1 = (const float*)d_in[13];
  const float* att_d1 = (const float*)d_in[14];
  const float* b_cnv1 = (const float*)d_in[15];
  const float* W_out  = (const float*)d_in[16];
  const float* b_out  = (const float*)d_in[17];
  float* out = (float*)d_out;

  const int N = in_sizes[0] / 128;
  const int E = in_sizes[1] / 2;
  const int NB = (N + 1023) / 1024;
  const int MB32 = (N + 31) / 32;
  const int SB = (E + 255) / 256;
  const int PACKB = (2 * 272 * 128 + 64 * 128 + 255) / 256;

  char* p = (char*)d_ws;
  unsigned int* ylin    = (unsigned int*)p;   p += (size_t)N * 64 * 4;
  unsigned short* xsb   = (unsigned short*)p; p += (size_t)N * 128 * 2;
  unsigned short* hb    = (unsigned short*)p; p += (size_t)N * 128 * 2;
  unsigned short* asd_s = (unsigned short*)p; p += (size_t)N * 8 * 2;
  unsigned short* asd_d = (unsigned short*)p; p += (size_t)N * 8 * 2;
  unsigned short* wt0   = (unsigned short*)p; p += (size_t)272 * 128 * 2;
  unsigned short* wt1   = (unsigned short*)p; p += (size_t)272 * 128 * 2;
  unsigned short* wot   = (unsigned short*)p; p += (size_t)64 * 128 * 2;
  int* rowptr = (int*)p;                      p += (size_t)(N + 4) * 4;
  int* cursor = (int*)p;                      p += (size_t)N * 4;
  int* deg    = (int*)p;                      p += (size_t)N * 4;
  int* lex    = (int*)p;                      p += (size_t)N * 4;
  int* bsum   = (int*)p;                      p += (size_t)256 * 4;
  unsigned short* col = (unsigned short*)p;   p += (size_t)E * 2;

  dim3 b256(256);

  hipMemsetAsync(deg, 0, (size_t)N * 4, stream);
  // pack all weights + degree count in one dispatch (independent block ranges)
  k_init<<<PACKB + SB, b256, 0, stream>>>(
      W_lin0, W_src0, W_dst0, att_s0, att_d0,
      W_lin1, W_src1, W_dst1, att_s1, att_d1,
      W_out, wt0, wt1, wot, ei, deg, E, PACKB);
  k_scan_local<<<NB, b256, 0, stream>>>(deg, lex, bsum, N);
  k_scan_bsum<<<1, b256, 0, stream>>>(bsum, NB);
  k_scan_add<<<(N + 256) / 256, b256, 0, stream>>>(lex, bsum, rowptr, cursor, N, E);

  // layer-0 GEMM ∪ CSR scatter, Bresenham-interleaved for co-residency
  k_gemm0_scatter<<<MB32 + SB, b256, 0, stream>>>(
      x, wt0, b_lin0, b_cnv0, ylin, xsb, asd_s, asd_d, N, MB32,
      ei, cursor, col, E, MB32 + SB);

  k_aggregate<<<(N + 3) / 4, b256, 0, stream>>>(
      ylin, (const unsigned int*)xsb, asd_s, asd_d, rowptr, col,
      (unsigned int*)hb, N);
  k_gemm_fused1<<<MB32, b256, 0, stream>>>(hb, wt1, b_lin1, b_cnv1,
                                           ylin, xsb, asd_s, asd_d, N);
  k_aggregate<<<(N + 3) / 4, b256, 0, stream>>>(
      ylin, (const unsigned int*)xsb, asd_s, asd_d, rowptr, col,
      (unsigned int*)hb, N);
  k_gemm_out<<<MB32, b256, 0, stream>>>(hb, wot, b_out, out, N);
}

// Round 14
// 157.777 us; speedup vs baseline: 1.3617x; 1.0477x over previous
//
#include <hip/hip_runtime.h>
#include <cstdint>
#include <cstddef>

#define NEG_SLOPE 0.2f

typedef __bf16 bf16x8 __attribute__((ext_vector_type(8)));
typedef float f32x4 __attribute__((ext_vector_type(4)));

static __device__ __forceinline__ unsigned short f2bf(float f) {
  unsigned int u = __float_as_uint(f);
  unsigned int r = (u + 0x7FFFu + ((u >> 16) & 1u)) >> 16;
  return (unsigned short)r;
}
static __device__ __forceinline__ float bf2f(unsigned short u) {
  return __uint_as_float(((unsigned int)u) << 16);
}
static __device__ __forceinline__ float pklo(unsigned int x) {
  return __uint_as_float(x << 16);
}
static __device__ __forceinline__ float pkhi(unsigned int x) {
  return __uint_as_float(x & 0xffff0000u);
}

// ---------------- CSR scan ----------------
__global__ __launch_bounds__(256) void k_scan_local(const int* __restrict__ deg,
                                                    int* __restrict__ lex,
                                                    int* __restrict__ bsum, int n) {
  __shared__ int ts[256];
  const int t = threadIdx.x;
  const int base = blockIdx.x * 1024 + t * 4;
  int4 d = {0, 0, 0, 0};
  if (base + 3 < n) d = *reinterpret_cast<const int4*>(&deg[base]);
  else {
    if (base + 0 < n) d.x = deg[base + 0];
    if (base + 1 < n) d.y = deg[base + 1];
    if (base + 2 < n) d.z = deg[base + 2];
  }
  int s = d.x + d.y + d.z + d.w;
  ts[t] = s;
  __syncthreads();
  for (int off = 1; off < 256; off <<= 1) {
    int y = (t >= off) ? ts[t - off] : 0;
    __syncthreads();
    ts[t] += y;
    __syncthreads();
  }
  int pre = ts[t] - s;
  int4 o;
  o.x = pre; o.y = pre + d.x; o.z = pre + d.x + d.y; o.w = pre + d.x + d.y + d.z;
  if (base + 3 < n) *reinterpret_cast<int4*>(&lex[base]) = o;
  else {
    if (base + 0 < n) lex[base + 0] = o.x;
    if (base + 1 < n) lex[base + 1] = o.y;
    if (base + 2 < n) lex[base + 2] = o.z;
  }
  if (t == 255) bsum[blockIdx.x] = ts[255];
}

// scan_add with embedded (redundant per-block) bsum exclusive scan — one
// launch instead of two.
__global__ __launch_bounds__(256) void k_scan_add(
    const int* __restrict__ lex, const int* __restrict__ bsum,
    int* __restrict__ rowptr, int n, int nb, int E) {
  __shared__ int ts[256];
  const int t = threadIdx.x;
  int v = (t < nb) ? bsum[t] : 0;
  ts[t] = v;
  __syncthreads();
  for (int off = 1; off < 256; off <<= 1) {
    int y = (t >= off) ? ts[t - off] : 0;
    __syncthreads();
    ts[t] += y;
    __syncthreads();
  }
  int excl = ts[t] - v;
  __syncthreads();
  ts[t] = excl;                       // ts[] now holds exclusive bsum scan
  __syncthreads();
  int i = blockIdx.x * 256 + t;
  if (i < n) rowptr[i] = lex[i] + ts[i >> 10];
  if (i == n) rowptr[n] = E;
}

// ---------------- k_init: weight pack ∪ degree count + edge rank ----------
static __device__ __forceinline__ unsigned short pack_wt_elem(
    const float* __restrict__ Wl, const float* __restrict__ Ws,
    const float* __restrict__ Wd, const float* __restrict__ as_,
    const float* __restrict__ ad_, int t) {
  int j = t >> 7, k = t & 127;
  float val;
  if (j < 128) val = Wl[k * 128 + j];
  else if (j < 256) val = Ws[k * 128 + (j - 128)];
  else {
    int jj = j - 256;
    int h = jj & 7;
    const float* W = (jj < 8) ? Ws : Wd;
    const float* a = (jj < 8) ? as_ : ad_;
    float s = 0.f;
#pragma unroll
    for (int c = 0; c < 16; ++c) s += W[k * 128 + h * 16 + c] * a[h * 16 + c];
    val = s;
  }
  return f2bf(val);
}

__global__ void k_init(
    const float* __restrict__ Wl0, const float* __restrict__ Ws0, const float* __restrict__ Wd0,
    const float* __restrict__ as0, const float* __restrict__ ad0,
    const float* __restrict__ Wl1, const float* __restrict__ Ws1, const float* __restrict__ Wd1,
    const float* __restrict__ as1, const float* __restrict__ ad1,
    const float* __restrict__ Wo,
    unsigned short* __restrict__ wt0, unsigned short* __restrict__ wt1,
    unsigned short* __restrict__ wot,
    const int* __restrict__ ei, int* __restrict__ deg,
    unsigned short* __restrict__ rank, int E, int packBlocks) {
  const int SZ = 272 * 128;
  if ((int)blockIdx.x < packBlocks) {
    int t = blockIdx.x * 256 + threadIdx.x;
    if (t < SZ) {
      wt0[t] = pack_wt_elem(Wl0, Ws0, Wd0, as0, ad0, t);
    } else if (t < 2 * SZ) {
      wt1[t - SZ] = pack_wt_elem(Wl1, Ws1, Wd1, as1, ad1, t - SZ);
    } else if (t < 2 * SZ + 64 * 128) {
      int u = t - 2 * SZ;
      int nn = u >> 7, k = u & 127;
      wot[u] = f2bf(Wo[k * 64 + nn]);
    }
  } else {
    int e = (blockIdx.x - packBlocks) * 256 + threadIdx.x;
    if (e < E)   // rank = old count: position of edge within its dst segment
      rank[e] = (unsigned short)atomicAdd(&deg[ei[E + e]], 1);
  }
}

// ---------------- k_gemm0_scatter: layer-0 GEMM ∪ atomic-free scatter -------
// Bresenham split over gemmBlocks : scatterBlocks so both kinds co-reside.
__global__ __launch_bounds__(256, 3) void k_gemm0_scatter(
    const float* __restrict__ X, const unsigned short* __restrict__ wt,
    const float* __restrict__ bl, const float* __restrict__ bc,
    unsigned int* __restrict__ ylin_pk, unsigned short* __restrict__ xsb,
    unsigned short* __restrict__ asd_s, unsigned short* __restrict__ asd_d,
    int n, int gemmBlocks,
    const int* __restrict__ ei, const int* __restrict__ rowptr,
    const unsigned short* __restrict__ rank,
    unsigned short* __restrict__ col, int E, int total) {
  __shared__ __align__(16) unsigned short xa[32][136];
  const int i = blockIdx.x;
  const int before = (int)(((long long)i * gemmBlocks) / total);
  const int after  = (int)(((long long)(i + 1) * gemmBlocks) / total);

  if (after == before) {           // ---- scatter block (no atomics) ----
    int e = (i - after) * 256 + threadIdx.x;
    if (e < E) {
      int d = ei[E + e];
      int pos = rowptr[d] + (int)rank[e];
      col[pos] = (unsigned short)ei[e];
    }
    return;
  }

  // ---- gemm block (tile index = before) ----
  const int tid = threadIdx.x;
  const int wave = tid >> 6, lane = tid & 63;
  const int lr = lane & 15, lg = lane >> 4;
  const int row0 = before * 32;
  const int f0 = wave * 4;
  const bool w3 = (wave == 3);

  bf16x8 bfr[4][4];
#pragma unroll
  for (int ff = 0; ff < 4; ++ff)
#pragma unroll
    for (int s = 0; s < 4; ++s)
      bfr[ff][s] = *reinterpret_cast<const bf16x8*>(
          &wt[(size_t)((f0 + ff) * 16 + lr) * 128 + s * 32 + lg * 8]);
  bf16x8 bfr4[4];
  if (w3) {
#pragma unroll
    for (int s = 0; s < 4; ++s)
      bfr4[s] = *reinterpret_cast<const bf16x8*>(
          &wt[(size_t)(256 + lr) * 128 + s * 32 + lg * 8]);
  }

#pragma unroll
  for (int ii = 0; ii < 4; ++ii) {
    int c = tid + ii * 256;
    int r = c >> 5, kq = c & 31;
    float4 v = make_float4(0.f, 0.f, 0.f, 0.f);
    if (row0 + r < n)
      v = reinterpret_cast<const float4*>(X)[(size_t)(row0 + r) * 32 + kq];
    ushort4 o;
    o.x = f2bf(v.x); o.y = f2bf(v.y); o.z = f2bf(v.z); o.w = f2bf(v.w);
    *reinterpret_cast<ushort4*>(&xa[r][kq * 4]) = o;
  }
  __syncthreads();

  f32x4 acc[2][4];
  f32x4 acc4[2];
#pragma unroll
  for (int g = 0; g < 2; ++g) {
    acc4[g] = (f32x4){0.f, 0.f, 0.f, 0.f};
#pragma unroll
    for (int ff = 0; ff < 4; ++ff) acc[g][ff] = (f32x4){0.f, 0.f, 0.f, 0.f};
  }

#pragma unroll
  for (int s = 0; s < 4; ++s) {
    bf16x8 a0 = *reinterpret_cast<const bf16x8*>(&xa[lr][s * 32 + lg * 8]);
    bf16x8 a1 = *reinterpret_cast<const bf16x8*>(&xa[16 + lr][s * 32 + lg * 8]);
#pragma unroll
    for (int ff = 0; ff < 4; ++ff) {
      acc[0][ff] = __builtin_amdgcn_mfma_f32_16x16x32_bf16(a0, bfr[ff][s], acc[0][ff], 0, 0, 0);
      acc[1][ff] = __builtin_amdgcn_mfma_f32_16x16x32_bf16(a1, bfr[ff][s], acc[1][ff], 0, 0, 0);
    }
    if (w3) {
      acc4[0] = __builtin_amdgcn_mfma_f32_16x16x32_bf16(a0, bfr4[s], acc4[0], 0, 0, 0);
      acc4[1] = __builtin_amdgcn_mfma_f32_16x16x32_bf16(a1, bfr4[s], acc4[1], 0, 0, 0);
    }
  }

  if (f0 < 8) {
#pragma unroll
    for (int g = 0; g < 2; ++g)
#pragma unroll
      for (int ff = 0; ff < 4; ++ff) {
        int j = (f0 + ff) * 16 + lr;
        float blc = bl[j] + bc[j];
#pragma unroll
        for (int r = 0; r < 4; ++r) {
          int row = row0 + g * 16 + lg * 4 + r;
          float vb = acc[g][ff][r] + blc;
          float v2 = __shfl(vb, lane ^ 1);
          if (row < n && (lr & 1) == 0)
            ylin_pk[(size_t)row * 64 + (j >> 1)] =
                (unsigned int)f2bf(vb) | ((unsigned int)f2bf(v2) << 16);
        }
      }
  } else {
#pragma unroll
    for (int g = 0; g < 2; ++g)
#pragma unroll
      for (int ff = 0; ff < 4; ++ff) {
        int j = (f0 - 8 + ff) * 16 + lr;
#pragma unroll
        for (int r = 0; r < 4; ++r) {
          int row = row0 + g * 16 + lg * 4 + r;
          if (row < n) xsb[(size_t)row * 128 + j] = f2bf(acc[g][ff][r]);
        }
      }
    if (w3) {
#pragma unroll
      for (int g = 0; g < 2; ++g)
#pragma unroll
        for (int r = 0; r < 4; ++r) {
          int row = row0 + g * 16 + lg * 4 + r;
          if (row < n) {
            unsigned short v = f2bf(acc4[g][r]);
            if (lr < 8) asd_s[(size_t)row * 8 + lr] = v;
            else        asd_d[(size_t)row * 8 + (lr - 8)] = v;
          }
        }
    }
  }
}

// ---------------- layer-1 fused MFMA GEMM (bf16 input, B in registers) --------
__global__ __launch_bounds__(256, 3) void k_gemm_fused1(
    const unsigned short* __restrict__ X, const unsigned short* __restrict__ wt,
    const float* __restrict__ bl, const float* __restrict__ bc,
    unsigned int* __restrict__ ylin_pk, unsigned short* __restrict__ xsb,
    unsigned short* __restrict__ asd_s, unsigned short* __restrict__ asd_d,
    int n) {
  __shared__ __align__(16) unsigned short xa[32][136];
  const int tid = threadIdx.x;
  const int wave = tid >> 6, lane = tid & 63;
  const int lr = lane & 15, lg = lane >> 4;
  const int row0 = blockIdx.x * 32;
  const int f0 = wave * 4;
  const bool w3 = (wave == 3);

  bf16x8 bfr[4][4];
#pragma unroll
  for (int ff = 0; ff < 4; ++ff)
#pragma unroll
    for (int s = 0; s < 4; ++s)
      bfr[ff][s] = *reinterpret_cast<const bf16x8*>(
          &wt[(size_t)((f0 + ff) * 16 + lr) * 128 + s * 32 + lg * 8]);
  bf16x8 bfr4[4];
  if (w3) {
#pragma unroll
    for (int s = 0; s < 4; ++s)
      bfr4[s] = *reinterpret_cast<const bf16x8*>(
          &wt[(size_t)(256 + lr) * 128 + s * 32 + lg * 8]);
  }

#pragma unroll
  for (int i = 0; i < 2; ++i) {
    int c = tid + i * 256;
    int r = c >> 4, ko = c & 15;
    uint4 v = {0u, 0u, 0u, 0u};
    if (row0 + r < n)
      v = reinterpret_cast<const uint4*>(X)[(size_t)(row0 + r) * 16 + ko];
    *reinterpret_cast<uint4*>(&xa[r][ko * 8]) = v;
  }
  __syncthreads();

  f32x4 acc[2][4];
  f32x4 acc4[2];
#pragma unroll
  for (int g = 0; g < 2; ++g) {
    acc4[g] = (f32x4){0.f, 0.f, 0.f, 0.f};
#pragma unroll
    for (int ff = 0; ff < 4; ++ff) acc[g][ff] = (f32x4){0.f, 0.f, 0.f, 0.f};
  }

#pragma unroll
  for (int s = 0; s < 4; ++s) {
    bf16x8 a0 = *reinterpret_cast<const bf16x8*>(&xa[lr][s * 32 + lg * 8]);
    bf16x8 a1 = *reinterpret_cast<const bf16x8*>(&xa[16 + lr][s * 32 + lg * 8]);
#pragma unroll
    for (int ff = 0; ff < 4; ++ff) {
      acc[0][ff] = __builtin_amdgcn_mfma_f32_16x16x32_bf16(a0, bfr[ff][s], acc[0][ff], 0, 0, 0);
      acc[1][ff] = __builtin_amdgcn_mfma_f32_16x16x32_bf16(a1, bfr[ff][s], acc[1][ff], 0, 0, 0);
    }
    if (w3) {
      acc4[0] = __builtin_amdgcn_mfma_f32_16x16x32_bf16(a0, bfr4[s], acc4[0], 0, 0, 0);
      acc4[1] = __builtin_amdgcn_mfma_f32_16x16x32_bf16(a1, bfr4[s], acc4[1], 0, 0, 0);
    }
  }

  if (f0 < 8) {
#pragma unroll
    for (int g = 0; g < 2; ++g)
#pragma unroll
      for (int ff = 0; ff < 4; ++ff) {
        int j = (f0 + ff) * 16 + lr;
        float blc = bl[j] + bc[j];
#pragma unroll
        for (int r = 0; r < 4; ++r) {
          int row = row0 + g * 16 + lg * 4 + r;
          float vb = acc[g][ff][r] + blc;
          float v2 = __shfl(vb, lane ^ 1);
          if (row < n && (lr & 1) == 0)
            ylin_pk[(size_t)row * 64 + (j >> 1)] =
                (unsigned int)f2bf(vb) | ((unsigned int)f2bf(v2) << 16);
        }
      }
  } else {
#pragma unroll
    for (int g = 0; g < 2; ++g)
#pragma unroll
      for (int ff = 0; ff < 4; ++ff) {
        int j = (f0 - 8 + ff) * 16 + lr;
#pragma unroll
        for (int r = 0; r < 4; ++r) {
          int row = row0 + g * 16 + lg * 4 + r;
          if (row < n) xsb[(size_t)row * 128 + j] = f2bf(acc[g][ff][r]);
        }
      }
    if (w3) {
#pragma unroll
      for (int g = 0; g < 2; ++g)
#pragma unroll
        for (int r = 0; r < 4; ++r) {
          int row = row0 + g * 16 + lg * 4 + r;
          if (row < n) {
            unsigned short v = f2bf(acc4[g][r]);
            if (lr < 8) asd_s[(size_t)row * 8 + lr] = v;
            else        asd_d[(size_t)row * 8 + (lr - 8)] = v;
          }
        }
    }
  }
}

// ---------------- final GEMM: out[N,64] = h@W_out + b (B in registers) --------
__global__ __launch_bounds__(256, 3) void k_gemm_out(
    const unsigned short* __restrict__ X, const unsigned short* __restrict__ wot,
    const float* __restrict__ bias, float* __restrict__ out, int n) {
  __shared__ __align__(16) unsigned short xa[32][136];
  const int tid = threadIdx.x;
  const int wave = tid >> 6, lane = tid & 63;
  const int lr = lane & 15, lg = lane >> 4;
  const int row0 = blockIdx.x * 32;

  bf16x8 bo[4];
#pragma unroll
  for (int s = 0; s < 4; ++s)
    bo[s] = *reinterpret_cast<const bf16x8*>(
        &wot[(size_t)(wave * 16 + lr) * 128 + s * 32 + lg * 8]);

#pragma unroll
  for (int i = 0; i < 2; ++i) {
    int c = tid + i * 256;
    int r = c >> 4, ko = c & 15;
    uint4 v = {0u, 0u, 0u, 0u};
    if (row0 + r < n)
      v = reinterpret_cast<const uint4*>(X)[(size_t)(row0 + r) * 16 + ko];
    *reinterpret_cast<uint4*>(&xa[r][ko * 8]) = v;
  }
  __syncthreads();

  f32x4 acc[2];
  acc[0] = (f32x4){0.f, 0.f, 0.f, 0.f};
  acc[1] = (f32x4){0.f, 0.f, 0.f, 0.f};
#pragma unroll
  for (int s = 0; s < 4; ++s) {
    bf16x8 a0 = *reinterpret_cast<const bf16x8*>(&xa[lr][s * 32 + lg * 8]);
    bf16x8 a1 = *reinterpret_cast<const bf16x8*>(&xa[16 + lr][s * 32 + lg * 8]);
    acc[0] = __builtin_amdgcn_mfma_f32_16x16x32_bf16(a0, bo[s], acc[0], 0, 0, 0);
    acc[1] = __builtin_amdgcn_mfma_f32_16x16x32_bf16(a1, bo[s], acc[1], 0, 0, 0);
  }
  float bv = bias[wave * 16 + lr];
#pragma unroll
  for (int g = 0; g < 2; ++g)
#pragma unroll
    for (int r = 0; r < 4; ++r) {
      int row = row0 + g * 16 + lg * 4 + r;
      if (row < n) out[(size_t)row * 64 + wave * 16 + lr] = acc[g][r] + bv;
    }
}

// ---------------- fused segment softmax + aggregation + node update ----------
// One wave per dst node. 16-edge software-pipelined chunks; branchless padding.
__global__ __launch_bounds__(256) void k_aggregate(
    const unsigned int* __restrict__ ylin_pk, const unsigned int* __restrict__ xsp,
    const unsigned short* __restrict__ asd_s, const unsigned short* __restrict__ asd_d,
    const int* __restrict__ rowptr, const unsigned short* __restrict__ col,
    unsigned int* __restrict__ hout_pk, int n) {
  int node = (blockIdx.x * blockDim.x + threadIdx.x) >> 6;
  if (node >= n) return;
  const int lane = threadIdx.x & 63;
  const int el = lane >> 3;
  const int hh = lane & 7;
  const int hb4 = (lane >> 3) << 2;
  const int beg = rowptr[node], end = rowptr[node + 1];

  const float ad_hh = bf2f(asd_d[(size_t)node * 8 + hh]);
  unsigned int y = __builtin_nontemporal_load(&ylin_pk[(size_t)node * 64 + lane]);

  float dsum = 0.f, acc0 = 0.f, acc1 = 0.f;
  int ebase = beg;
  for (; ebase + 8 < end; ebase += 16) {
    int eA = ebase + el;
    int eB = ebase + 8 + el;
    bool vB = eB < end;
    int esB = vB ? eB : (end - 1);
    int srcA = (int)__builtin_nontemporal_load(&col[eA]);
    int srcB = (int)__builtin_nontemporal_load(&col[esB]);
    float svA = bf2f(asd_s[(size_t)srcA * 8 + hh]) + ad_hh;
    float svB = bf2f(asd_s[(size_t)srcB * 8 + hh]) + ad_hh;
    svA = fmaxf(svA, NEG_SLOPE * svA);
    svB = fmaxf(svB, NEG_SLOPE * svB);
    float peA = __expf(svA);
    float peB = vB ? __expf(svB) : 0.f;
#pragma unroll
    for (int q = 0; q < 8; ++q) {
      float pq = __uint_as_float(__builtin_amdgcn_ds_bpermute(
          q * 32 + hb4, __float_as_uint(peA)));
      int sq = __builtin_amdgcn_readlane(srcA, q * 8);
      unsigned int xv = xsp[(size_t)sq * 64 + lane];
      dsum += pq;
      acc0 += pq * pklo(xv);
      acc1 += pq * pkhi(xv);
    }
#pragma unroll
    for (int q = 0; q < 8; ++q) {
      float pq = __uint_as_float(__builtin_amdgcn_ds_bpermute(
          q * 32 + hb4, __float_as_uint(peB)));
      int sq = __builtin_amdgcn_readlane(srcB, q * 8);
      unsigned int xv = xsp[(size_t)sq * 64 + lane];
      dsum += pq;
      acc0 += pq * pklo(xv);
      acc1 += pq * pkhi(xv);
    }
  }
  for (; ebase < end; ebase += 8) {
    int e1 = ebase + el;
    bool valid = e1 < end;
    int esafe = valid ? e1 : (end - 1);
    int srcp = (int)__builtin_nontemporal_load(&col[esafe]);
    float sv = bf2f(asd_s[(size_t)srcp * 8 + hh]) + ad_hh;
    sv = fmaxf(sv, NEG_SLOPE * sv);
    float pe = valid ? __expf(sv) : 0.f;
#pragma unroll
    for (int q = 0; q < 8; ++q) {
      float pq = __uint_as_float(__builtin_amdgcn_ds_bpermute(
          q * 32 + hb4, __float_as_uint(pe)));
      int sq = __builtin_amdgcn_readlane(srcp, q * 8);
      unsigned int xv = xsp[(size_t)sq * 64 + lane];
      dsum += pq;
      acc0 += pq * pklo(xv);
      acc1 += pq * pkhi(xv);
    }
  }
  float inv = 1.f / (dsum + 1e-16f);
  float l0 = pklo(y) + acc0 * inv;
  float l1 = pkhi(y) + acc1 * inv;
  l0 = l0 > 0.f ? l0 : __expf(l0) - 1.f;
  l1 = l1 > 0.f ? l1 : __expf(l1) - 1.f;
  hout_pk[(size_t)node * 64 + lane] =
      (unsigned int)f2bf(l0) | ((unsigned int)f2bf(l1) << 16);
}

// ---------------- launch ----------------
extern "C" void kernel_launch(void* const* d_in, const int* in_sizes, int n_in,
                              void* d_out, int out_size, void* d_ws, size_t ws_size,
                              hipStream_t stream) {
  const float* x      = (const float*)d_in[0];
  const int*   ei     = (const int*)d_in[1];
  const float* W_lin0 = (const float*)d_in[2];
  const float* b_lin0 = (const float*)d_in[3];
  const float* W_src0 = (const float*)d_in[4];
  const float* W_dst0 = (const float*)d_in[5];
  const float* att_s0 = (const float*)d_in[6];
  const float* att_d0 = (const float*)d_in[7];
  const float* b_cnv0 = (const float*)d_in[8];
  const float* W_lin1 = (const float*)d_in[9];
  const float* b_lin1 = (const float*)d_in[10];
  const float* W_src1 = (const float*)d_in[11];
  const float* W_dst1 = (const float*)d_in[12];
  const float* att_s1 = (const float*)d_in[13];
  const float* att_d1 = (const float*)d_in[14];
  const float* b_cnv1 = (const float*)d_in[15];
  const float* W_out  = (const float*)d_in[16];
  const float* b_out  = (const float*)d_in[17];
  float* out = (float*)d_out;

  const int N = in_sizes[0] / 128;
  const int E = in_sizes[1] / 2;
  const int NB = (N + 1023) / 1024;
  const int MB32 = (N + 31) / 32;
  const int SB = (E + 255) / 256;
  const int PACKB = (2 * 272 * 128 + 64 * 128 + 255) / 256;

  char* p = (char*)d_ws;
  unsigned int* ylin    = (unsigned int*)p;   p += (size_t)N * 64 * 4;
  unsigned short* xsb   = (unsigned short*)p; p += (size_t)N * 128 * 2;
  unsigned short* hb    = (unsigned short*)p; p += (size_t)N * 128 * 2;
  unsigned short* asd_s = (unsigned short*)p; p += (size_t)N * 8 * 2;
  unsigned short* asd_d = (unsigned short*)p; p += (size_t)N * 8 * 2;
  unsigned short* wt0   = (unsigned short*)p; p += (size_t)272 * 128 * 2;
  unsigned short* wt1   = (unsigned short*)p; p += (size_t)272 * 128 * 2;
  unsigned short* wot   = (unsigned short*)p; p += (size_t)64 * 128 * 2;
  int* rowptr = (int*)p;                      p += (size_t)(N + 4) * 4;
  int* deg    = (int*)p;                      p += (size_t)N * 4;
  int* lex    = (int*)p;                      p += (size_t)N * 4;
  int* bsum   = (int*)p;                      p += (size_t)256 * 4;
  unsigned short* col  = (unsigned short*)p;  p += (size_t)E * 2;
  unsigned short* rank = (unsigned short*)p;  p += (size_t)E * 2;

  dim3 b256(256);

  hipMemsetAsync(deg, 0, (size_t)N * 4, stream);
  // pack all weights ∪ degree count + per-edge rank (one dispatch)
  k_init<<<PACKB + SB, b256, 0, stream>>>(
      W_lin0, W_src0, W_dst0, att_s0, att_d0,
      W_lin1, W_src1, W_dst1, att_s1, att_d1,
      W_out, wt0, wt1, wot, ei, deg, rank, E, PACKB);
  k_scan_local<<<NB, b256, 0, stream>>>(deg, lex, bsum, N);
  k_scan_add<<<(N + 256) / 256, b256, 0, stream>>>(lex, bsum, rowptr, N, NB, E);

  // layer-0 GEMM ∪ atomic-free CSR scatter, Bresenham-interleaved
  k_gemm0_scatter<<<MB32 + SB, b256, 0, stream>>>(
      x, wt0, b_lin0, b_cnv0, ylin, xsb, asd_s, asd_d, N, MB32,
      ei, rowptr, rank, col, E, MB32 + SB);

  k_aggregate<<<(N + 3) / 4, b256, 0, stream>>>(
      ylin, (const unsigned int*)xsb, asd_s, asd_d, rowptr, col,
      (unsigned int*)hb, N);
  k_gemm_fused1<<<MB32, b256, 0, stream>>>(hb, wt1, b_lin1, b_cnv1,
                                           ylin, xsb, asd_s, asd_d, N);
  k_aggregate<<<(N + 3) / 4, b256, 0, stream>>>(
      ylin, (const unsigned int*)xsb, asd_s, asd_d, rowptr, col,
      (unsigned int*)hb, N);
  k_gemm_out<<<MB32, b256, 0, stream>>>(hb, wot, b_out, out, N);
}

// Round 15
// 156.302 us; speedup vs baseline: 1.3746x; 1.0094x over previous
//
#include <hip/hip_runtime.h>
#include <cstdint>
#include <cstddef>

#define NEG_SLOPE 0.2f

typedef __bf16 bf16x8 __attribute__((ext_vector_type(8)));
typedef float f32x4 __attribute__((ext_vector_type(4)));

static __device__ __forceinline__ unsigned short f2bf(float f) {
  unsigned int u = __float_as_uint(f);
  unsigned int r = (u + 0x7FFFu + ((u >> 16) & 1u)) >> 16;
  return (unsigned short)r;
}
static __device__ __forceinline__ float bf2f(unsigned short u) {
  return __uint_as_float(((unsigned int)u) << 16);
}
static __device__ __forceinline__ float pklo(unsigned int x) {
  return __uint_as_float(x << 16);
}
static __device__ __forceinline__ float pkhi(unsigned int x) {
  return __uint_as_float(x & 0xffff0000u);
}

// ---------------- CSR scan ----------------
__global__ __launch_bounds__(256) void k_scan_local(const int* __restrict__ deg,
                                                    int* __restrict__ lex,
                                                    int* __restrict__ bsum, int n) {
  __shared__ int ts[256];
  const int t = threadIdx.x;
  const int base = blockIdx.x * 1024 + t * 4;
  int4 d = {0, 0, 0, 0};
  if (base + 3 < n) d = *reinterpret_cast<const int4*>(&deg[base]);
  else {
    if (base + 0 < n) d.x = deg[base + 0];
    if (base + 1 < n) d.y = deg[base + 1];
    if (base + 2 < n) d.z = deg[base + 2];
  }
  int s = d.x + d.y + d.z + d.w;
  ts[t] = s;
  __syncthreads();
  for (int off = 1; off < 256; off <<= 1) {
    int y = (t >= off) ? ts[t - off] : 0;
    __syncthreads();
    ts[t] += y;
    __syncthreads();
  }
  int pre = ts[t] - s;
  int4 o;
  o.x = pre; o.y = pre + d.x; o.z = pre + d.x + d.y; o.w = pre + d.x + d.y + d.z;
  if (base + 3 < n) *reinterpret_cast<int4*>(&lex[base]) = o;
  else {
    if (base + 0 < n) lex[base + 0] = o.x;
    if (base + 1 < n) lex[base + 1] = o.y;
    if (base + 2 < n) lex[base + 2] = o.z;
  }
  if (t == 255) bsum[blockIdx.x] = ts[255];
}

// scan_add with embedded (redundant per-block) bsum exclusive scan.
__global__ __launch_bounds__(256) void k_scan_add(
    const int* __restrict__ lex, const int* __restrict__ bsum,
    int* __restrict__ rowptr, int n, int nb, int E) {
  __shared__ int ts[256];
  const int t = threadIdx.x;
  int v = (t < nb) ? bsum[t] : 0;
  ts[t] = v;
  __syncthreads();
  for (int off = 1; off < 256; off <<= 1) {
    int y = (t >= off) ? ts[t - off] : 0;
    __syncthreads();
    ts[t] += y;
    __syncthreads();
  }
  int excl = ts[t] - v;
  __syncthreads();
  ts[t] = excl;
  __syncthreads();
  int i = blockIdx.x * 256 + t;
  if (i < n) rowptr[i] = lex[i] + ts[i >> 10];
  if (i == n) rowptr[n] = E;
}

// ---------------- k_init: weight pack ∪ degree count + edge rank (4/thread) --
static __device__ __forceinline__ unsigned short pack_wt_elem(
    const float* __restrict__ Wl, const float* __restrict__ Ws,
    const float* __restrict__ Wd, const float* __restrict__ as_,
    const float* __restrict__ ad_, int t) {
  int j = t >> 7, k = t & 127;
  float val;
  if (j < 128) val = Wl[k * 128 + j];
  else if (j < 256) val = Ws[k * 128 + (j - 128)];
  else {
    int jj = j - 256;
    int h = jj & 7;
    const float* W = (jj < 8) ? Ws : Wd;
    const float* a = (jj < 8) ? as_ : ad_;
    float s = 0.f;
#pragma unroll
    for (int c = 0; c < 16; ++c) s += W[k * 128 + h * 16 + c] * a[h * 16 + c];
    val = s;
  }
  return f2bf(val);
}

__global__ void k_init(
    const float* __restrict__ Wl0, const float* __restrict__ Ws0, const float* __restrict__ Wd0,
    const float* __restrict__ as0, const float* __restrict__ ad0,
    const float* __restrict__ Wl1, const float* __restrict__ Ws1, const float* __restrict__ Wd1,
    const float* __restrict__ as1, const float* __restrict__ ad1,
    const float* __restrict__ Wo,
    unsigned short* __restrict__ wt0, unsigned short* __restrict__ wt1,
    unsigned short* __restrict__ wot,
    const int* __restrict__ ei, int* __restrict__ deg,
    unsigned short* __restrict__ rank, int E, int packBlocks) {
  const int SZ = 272 * 128;
  if ((int)blockIdx.x < packBlocks) {
    int t = blockIdx.x * 256 + threadIdx.x;
    if (t < SZ) {
      wt0[t] = pack_wt_elem(Wl0, Ws0, Wd0, as0, ad0, t);
    } else if (t < 2 * SZ) {
      wt1[t - SZ] = pack_wt_elem(Wl1, Ws1, Wd1, as1, ad1, t - SZ);
    } else if (t < 2 * SZ + 64 * 128) {
      int u = t - 2 * SZ;
      int nn = u >> 7, k = u & 127;
      wot[u] = f2bf(Wo[k * 64 + nn]);
    }
  } else {
    // 4 edges per thread: vector dst load, 4 independent atomics in flight
    int e = ((blockIdx.x - packBlocks) * 256 + threadIdx.x) * 4;
    if (e + 3 < E) {
      int4 d4 = *reinterpret_cast<const int4*>(&ei[E + e]);
      ushort4 r4;
      r4.x = (unsigned short)atomicAdd(&deg[d4.x], 1);
      r4.y = (unsigned short)atomicAdd(&deg[d4.y], 1);
      r4.z = (unsigned short)atomicAdd(&deg[d4.z], 1);
      r4.w = (unsigned short)atomicAdd(&deg[d4.w], 1);
      *reinterpret_cast<ushort4*>(&rank[e]) = r4;
    } else {
      for (int q = 0; q < 4 && e + q < E; ++q)
        rank[e + q] = (unsigned short)atomicAdd(&deg[ei[E + e + q]], 1);
    }
  }
}

// ---------------- k_gemm0_scatter: layer-0 GEMM ∪ atomic-free scatter -------
// Bresenham split over gemmBlocks : scatterBlocks. Scatter: 4 edges/thread.
__global__ __launch_bounds__(256, 3) void k_gemm0_scatter(
    const float* __restrict__ X, const unsigned short* __restrict__ wt,
    const float* __restrict__ bl, const float* __restrict__ bc,
    unsigned int* __restrict__ ylin_pk, unsigned short* __restrict__ xsb,
    unsigned short* __restrict__ asd_s, unsigned short* __restrict__ asd_d,
    int n, int gemmBlocks,
    const int* __restrict__ ei, const int* __restrict__ rowptr,
    const unsigned short* __restrict__ rank,
    unsigned short* __restrict__ col, int E, int total) {
  __shared__ __align__(16) unsigned short xa[32][136];
  const int i = blockIdx.x;
  const int before = (int)(((long long)i * gemmBlocks) / total);
  const int after  = (int)(((long long)(i + 1) * gemmBlocks) / total);

  if (after == before) {           // ---- scatter block (no atomics, 4/thread) ----
    int e = ((i - after) * 256 + threadIdx.x) * 4;
    if (e + 3 < E) {
      int4 s4 = *reinterpret_cast<const int4*>(&ei[e]);
      int4 d4 = *reinterpret_cast<const int4*>(&ei[E + e]);
      ushort4 r4 = *reinterpret_cast<const ushort4*>(&rank[e]);
      int p0 = rowptr[d4.x] + (int)r4.x;
      int p1 = rowptr[d4.y] + (int)r4.y;
      int p2 = rowptr[d4.z] + (int)r4.z;
      int p3 = rowptr[d4.w] + (int)r4.w;
      col[p0] = (unsigned short)s4.x;
      col[p1] = (unsigned short)s4.y;
      col[p2] = (unsigned short)s4.z;
      col[p3] = (unsigned short)s4.w;
    } else {
      for (int q = 0; q < 4 && e + q < E; ++q) {
        int d = ei[E + e + q];
        col[rowptr[d] + (int)rank[e + q]] = (unsigned short)ei[e + q];
      }
    }
    return;
  }

  // ---- gemm block (tile index = before) ----
  const int tid = threadIdx.x;
  const int wave = tid >> 6, lane = tid & 63;
  const int lr = lane & 15, lg = lane >> 4;
  const int row0 = before * 32;
  const int f0 = wave * 4;
  const bool w3 = (wave == 3);

  bf16x8 bfr[4][4];
#pragma unroll
  for (int ff = 0; ff < 4; ++ff)
#pragma unroll
    for (int s = 0; s < 4; ++s)
      bfr[ff][s] = *reinterpret_cast<const bf16x8*>(
          &wt[(size_t)((f0 + ff) * 16 + lr) * 128 + s * 32 + lg * 8]);
  bf16x8 bfr4[4];
  if (w3) {
#pragma unroll
    for (int s = 0; s < 4; ++s)
      bfr4[s] = *reinterpret_cast<const bf16x8*>(
          &wt[(size_t)(256 + lr) * 128 + s * 32 + lg * 8]);
  }

#pragma unroll
  for (int ii = 0; ii < 4; ++ii) {
    int c = tid + ii * 256;
    int r = c >> 5, kq = c & 31;
    float4 v = make_float4(0.f, 0.f, 0.f, 0.f);
    if (row0 + r < n)
      v = reinterpret_cast<const float4*>(X)[(size_t)(row0 + r) * 32 + kq];
    ushort4 o;
    o.x = f2bf(v.x); o.y = f2bf(v.y); o.z = f2bf(v.z); o.w = f2bf(v.w);
    *reinterpret_cast<ushort4*>(&xa[r][kq * 4]) = o;
  }
  __syncthreads();

  f32x4 acc[2][4];
  f32x4 acc4[2];
#pragma unroll
  for (int g = 0; g < 2; ++g) {
    acc4[g] = (f32x4){0.f, 0.f, 0.f, 0.f};
#pragma unroll
    for (int ff = 0; ff < 4; ++ff) acc[g][ff] = (f32x4){0.f, 0.f, 0.f, 0.f};
  }

#pragma unroll
  for (int s = 0; s < 4; ++s) {
    bf16x8 a0 = *reinterpret_cast<const bf16x8*>(&xa[lr][s * 32 + lg * 8]);
    bf16x8 a1 = *reinterpret_cast<const bf16x8*>(&xa[16 + lr][s * 32 + lg * 8]);
#pragma unroll
    for (int ff = 0; ff < 4; ++ff) {
      acc[0][ff] = __builtin_amdgcn_mfma_f32_16x16x32_bf16(a0, bfr[ff][s], acc[0][ff], 0, 0, 0);
      acc[1][ff] = __builtin_amdgcn_mfma_f32_16x16x32_bf16(a1, bfr[ff][s], acc[1][ff], 0, 0, 0);
    }
    if (w3) {
      acc4[0] = __builtin_amdgcn_mfma_f32_16x16x32_bf16(a0, bfr4[s], acc4[0], 0, 0, 0);
      acc4[1] = __builtin_amdgcn_mfma_f32_16x16x32_bf16(a1, bfr4[s], acc4[1], 0, 0, 0);
    }
  }

  if (f0 < 8) {
#pragma unroll
    for (int g = 0; g < 2; ++g)
#pragma unroll
      for (int ff = 0; ff < 4; ++ff) {
        int j = (f0 + ff) * 16 + lr;
        float blc = bl[j] + bc[j];
#pragma unroll
        for (int r = 0; r < 4; ++r) {
          int row = row0 + g * 16 + lg * 4 + r;
          float vb = acc[g][ff][r] + blc;
          float v2 = __shfl(vb, lane ^ 1);
          if (row < n && (lr & 1) == 0)
            ylin_pk[(size_t)row * 64 + (j >> 1)] =
                (unsigned int)f2bf(vb) | ((unsigned int)f2bf(v2) << 16);
        }
      }
  } else {
#pragma unroll
    for (int g = 0; g < 2; ++g)
#pragma unroll
      for (int ff = 0; ff < 4; ++ff) {
        int j = (f0 - 8 + ff) * 16 + lr;
#pragma unroll
        for (int r = 0; r < 4; ++r) {
          int row = row0 + g * 16 + lg * 4 + r;
          if (row < n) xsb[(size_t)row * 128 + j] = f2bf(acc[g][ff][r]);
        }
      }
    if (w3) {
#pragma unroll
      for (int g = 0; g < 2; ++g)
#pragma unroll
        for (int r = 0; r < 4; ++r) {
          int row = row0 + g * 16 + lg * 4 + r;
          if (row < n) {
            unsigned short v = f2bf(acc4[g][r]);
            if (lr < 8) asd_s[(size_t)row * 8 + lr] = v;
            else        asd_d[(size_t)row * 8 + (lr - 8)] = v;
          }
        }
    }
  }
}

// ---------------- layer-1 fused MFMA GEMM (bf16 input, B in registers) --------
__global__ __launch_bounds__(256, 3) void k_gemm_fused1(
    const unsigned short* __restrict__ X, const unsigned short* __restrict__ wt,
    const float* __restrict__ bl, const float* __restrict__ bc,
    unsigned int* __restrict__ ylin_pk, unsigned short* __restrict__ xsb,
    unsigned short* __restrict__ asd_s, unsigned short* __restrict__ asd_d,
    int n) {
  __shared__ __align__(16) unsigned short xa[32][136];
  const int tid = threadIdx.x;
  const int wave = tid >> 6, lane = tid & 63;
  const int lr = lane & 15, lg = lane >> 4;
  const int row0 = blockIdx.x * 32;
  const int f0 = wave * 4;
  const bool w3 = (wave == 3);

  bf16x8 bfr[4][4];
#pragma unroll
  for (int ff = 0; ff < 4; ++ff)
#pragma unroll
    for (int s = 0; s < 4; ++s)
      bfr[ff][s] = *reinterpret_cast<const bf16x8*>(
          &wt[(size_t)((f0 + ff) * 16 + lr) * 128 + s * 32 + lg * 8]);
  bf16x8 bfr4[4];
  if (w3) {
#pragma unroll
    for (int s = 0; s < 4; ++s)
      bfr4[s] = *reinterpret_cast<const bf16x8*>(
          &wt[(size_t)(256 + lr) * 128 + s * 32 + lg * 8]);
  }

#pragma unroll
  for (int i = 0; i < 2; ++i) {
    int c = tid + i * 256;
    int r = c >> 4, ko = c & 15;
    uint4 v = {0u, 0u, 0u, 0u};
    if (row0 + r < n)
      v = reinterpret_cast<const uint4*>(X)[(size_t)(row0 + r) * 16 + ko];
    *reinterpret_cast<uint4*>(&xa[r][ko * 8]) = v;
  }
  __syncthreads();

  f32x4 acc[2][4];
  f32x4 acc4[2];
#pragma unroll
  for (int g = 0; g < 2; ++g) {
    acc4[g] = (f32x4){0.f, 0.f, 0.f, 0.f};
#pragma unroll
    for (int ff = 0; ff < 4; ++ff) acc[g][ff] = (f32x4){0.f, 0.f, 0.f, 0.f};
  }

#pragma unroll
  for (int s = 0; s < 4; ++s) {
    bf16x8 a0 = *reinterpret_cast<const bf16x8*>(&xa[lr][s * 32 + lg * 8]);
    bf16x8 a1 = *reinterpret_cast<const bf16x8*>(&xa[16 + lr][s * 32 + lg * 8]);
#pragma unroll
    for (int ff = 0; ff < 4; ++ff) {
      acc[0][ff] = __builtin_amdgcn_mfma_f32_16x16x32_bf16(a0, bfr[ff][s], acc[0][ff], 0, 0, 0);
      acc[1][ff] = __builtin_amdgcn_mfma_f32_16x16x32_bf16(a1, bfr[ff][s], acc[1][ff], 0, 0, 0);
    }
    if (w3) {
      acc4[0] = __builtin_amdgcn_mfma_f32_16x16x32_bf16(a0, bfr4[s], acc4[0], 0, 0, 0);
      acc4[1] = __builtin_amdgcn_mfma_f32_16x16x32_bf16(a1, bfr4[s], acc4[1], 0, 0, 0);
    }
  }

  if (f0 < 8) {
#pragma unroll
    for (int g = 0; g < 2; ++g)
#pragma unroll
      for (int ff = 0; ff < 4; ++ff) {
        int j = (f0 + ff) * 16 + lr;
        float blc = bl[j] + bc[j];
#pragma unroll
        for (int r = 0; r < 4; ++r) {
          int row = row0 + g * 16 + lg * 4 + r;
          float vb = acc[g][ff][r] + blc;
          float v2 = __shfl(vb, lane ^ 1);
          if (row < n && (lr & 1) == 0)
            ylin_pk[(size_t)row * 64 + (j >> 1)] =
                (unsigned int)f2bf(vb) | ((unsigned int)f2bf(v2) << 16);
        }
      }
  } else {
#pragma unroll
    for (int g = 0; g < 2; ++g)
#pragma unroll
      for (int ff = 0; ff < 4; ++ff) {
        int j = (f0 - 8 + ff) * 16 + lr;
#pragma unroll
        for (int r = 0; r < 4; ++r) {
          int row = row0 + g * 16 + lg * 4 + r;
          if (row < n) xsb[(size_t)row * 128 + j] = f2bf(acc[g][ff][r]);
        }
      }
    if (w3) {
#pragma unroll
      for (int g = 0; g < 2; ++g)
#pragma unroll
        for (int r = 0; r < 4; ++r) {
          int row = row0 + g * 16 + lg * 4 + r;
          if (row < n) {
            unsigned short v = f2bf(acc4[g][r]);
            if (lr < 8) asd_s[(size_t)row * 8 + lr] = v;
            else        asd_d[(size_t)row * 8 + (lr - 8)] = v;
          }
        }
    }
  }
}

// ---------------- final GEMM: out[N,64] = h@W_out + b (B in registers) --------
__global__ __launch_bounds__(256, 3) void k_gemm_out(
    const unsigned short* __restrict__ X, const unsigned short* __restrict__ wot,
    const float* __restrict__ bias, float* __restrict__ out, int n) {
  __shared__ __align__(16) unsigned short xa[32][136];
  const int tid = threadIdx.x;
  const int wave = tid >> 6, lane = tid & 63;
  const int lr = lane & 15, lg = lane >> 4;
  const int row0 = blockIdx.x * 32;

  bf16x8 bo[4];
#pragma unroll
  for (int s = 0; s < 4; ++s)
    bo[s] = *reinterpret_cast<const bf16x8*>(
        &wot[(size_t)(wave * 16 + lr) * 128 + s * 32 + lg * 8]);

#pragma unroll
  for (int i = 0; i < 2; ++i) {
    int c = tid + i * 256;
    int r = c >> 4, ko = c & 15;
    uint4 v = {0u, 0u, 0u, 0u};
    if (row0 + r < n)
      v = reinterpret_cast<const uint4*>(X)[(size_t)(row0 + r) * 16 + ko];
    *reinterpret_cast<uint4*>(&xa[r][ko * 8]) = v;
  }
  __syncthreads();

  f32x4 acc[2];
  acc[0] = (f32x4){0.f, 0.f, 0.f, 0.f};
  acc[1] = (f32x4){0.f, 0.f, 0.f, 0.f};
#pragma unroll
  for (int s = 0; s < 4; ++s) {
    bf16x8 a0 = *reinterpret_cast<const bf16x8*>(&xa[lr][s * 32 + lg * 8]);
    bf16x8 a1 = *reinterpret_cast<const bf16x8*>(&xa[16 + lr][s * 32 + lg * 8]);
    acc[0] = __builtin_amdgcn_mfma_f32_16x16x32_bf16(a0, bo[s], acc[0], 0, 0, 0);
    acc[1] = __builtin_amdgcn_mfma_f32_16x16x32_bf16(a1, bo[s], acc[1], 0, 0, 0);
  }
  float bv = bias[wave * 16 + lr];
#pragma unroll
  for (int g = 0; g < 2; ++g)
#pragma unroll
    for (int r = 0; r < 4; ++r) {
      int row = row0 + g * 16 + lg * 4 + r;
      if (row < n) out[(size_t)row * 64 + wave * 16 + lr] = acc[g][r] + bv;
    }
}

// ---------------- fused segment softmax + aggregation + node update ----------
// One wave per dst node. 16-edge software-pipelined chunks; branchless padding.
__global__ __launch_bounds__(256) void k_aggregate(
    const unsigned int* __restrict__ ylin_pk, const unsigned int* __restrict__ xsp,
    const unsigned short* __restrict__ asd_s, const unsigned short* __restrict__ asd_d,
    const int* __restrict__ rowptr, const unsigned short* __restrict__ col,
    unsigned int* __restrict__ hout_pk, int n) {
  int node = (blockIdx.x * blockDim.x + threadIdx.x) >> 6;
  if (node >= n) return;
  const int lane = threadIdx.x & 63;
  const int el = lane >> 3;
  const int hh = lane & 7;
  const int hb4 = (lane >> 3) << 2;
  const int beg = rowptr[node], end = rowptr[node + 1];

  const float ad_hh = bf2f(asd_d[(size_t)node * 8 + hh]);
  unsigned int y = __builtin_nontemporal_load(&ylin_pk[(size_t)node * 64 + lane]);

  float dsum = 0.f, acc0 = 0.f, acc1 = 0.f;
  int ebase = beg;
  for (; ebase + 8 < end; ebase += 16) {
    int eA = ebase + el;
    int eB = ebase + 8 + el;
    bool vB = eB < end;
    int esB = vB ? eB : (end - 1);
    int srcA = (int)__builtin_nontemporal_load(&col[eA]);
    int srcB = (int)__builtin_nontemporal_load(&col[esB]);
    float svA = bf2f(asd_s[(size_t)srcA * 8 + hh]) + ad_hh;
    float svB = bf2f(asd_s[(size_t)srcB * 8 + hh]) + ad_hh;
    svA = fmaxf(svA, NEG_SLOPE * svA);
    svB = fmaxf(svB, NEG_SLOPE * svB);
    float peA = __expf(svA);
    float peB = vB ? __expf(svB) : 0.f;
#pragma unroll
    for (int q = 0; q < 8; ++q) {
      float pq = __uint_as_float(__builtin_amdgcn_ds_bpermute(
          q * 32 + hb4, __float_as_uint(peA)));
      int sq = __builtin_amdgcn_readlane(srcA, q * 8);
      unsigned int xv = xsp[(size_t)sq * 64 + lane];
      dsum += pq;
      acc0 += pq * pklo(xv);
      acc1 += pq * pkhi(xv);
    }
#pragma unroll
    for (int q = 0; q < 8; ++q) {
      float pq = __uint_as_float(__builtin_amdgcn_ds_bpermute(
          q * 32 + hb4, __float_as_uint(peB)));
      int sq = __builtin_amdgcn_readlane(srcB, q * 8);
      unsigned int xv = xsp[(size_t)sq * 64 + lane];
      dsum += pq;
      acc0 += pq * pklo(xv);
      acc1 += pq * pkhi(xv);
    }
  }
  for (; ebase < end; ebase += 8) {
    int e1 = ebase + el;
    bool valid = e1 < end;
    int esafe = valid ? e1 : (end - 1);
    int srcp = (int)__builtin_nontemporal_load(&col[esafe]);
    float sv = bf2f(asd_s[(size_t)srcp * 8 + hh]) + ad_hh;
    sv = fmaxf(sv, NEG_SLOPE * sv);
    float pe = valid ? __expf(sv) : 0.f;
#pragma unroll
    for (int q = 0; q < 8; ++q) {
      float pq = __uint_as_float(__builtin_amdgcn_ds_bpermute(
          q * 32 + hb4, __float_as_uint(pe)));
      int sq = __builtin_amdgcn_readlane(srcp, q * 8);
      unsigned int xv = xsp[(size_t)sq * 64 + lane];
      dsum += pq;
      acc0 += pq * pklo(xv);
      acc1 += pq * pkhi(xv);
    }
  }
  float inv = 1.f / (dsum + 1e-16f);
  float l0 = pklo(y) + acc0 * inv;
  float l1 = pkhi(y) + acc1 * inv;
  l0 = l0 > 0.f ? l0 : __expf(l0) - 1.f;
  l1 = l1 > 0.f ? l1 : __expf(l1) - 1.f;
  hout_pk[(size_t)node * 64 + lane] =
      (unsigned int)f2bf(l0) | ((unsigned int)f2bf(l1) << 16);
}

// ---------------- launch ----------------
extern "C" void kernel_launch(void* const* d_in, const int* in_sizes, int n_in,
                              void* d_out, int out_size, void* d_ws, size_t ws_size,
                              hipStream_t stream) {
  const float* x      = (const float*)d_in[0];
  const int*   ei     = (const int*)d_in[1];
  const float* W_lin0 = (const float*)d_in[2];
  const float* b_lin0 = (const float*)d_in[3];
  const float* W_src0 = (const float*)d_in[4];
  const float* W_dst0 = (const float*)d_in[5];
  const float* att_s0 = (const float*)d_in[6];
  const float* att_d0 = (const float*)d_in[7];
  const float* b_cnv0 = (const float*)d_in[8];
  const float* W_lin1 = (const float*)d_in[9];
  const float* b_lin1 = (const float*)d_in[10];
  const float* W_src1 = (const float*)d_in[11];
  const float* W_dst1 = (const float*)d_in[12];
  const float* att_s1 = (const float*)d_in[13];
  const float* att_d1 = (const float*)d_in[14];
  const float* b_cnv1 = (const float*)d_in[15];
  const float* W_out  = (const float*)d_in[16];
  const float* b_out  = (const float*)d_in[17];
  float* out = (float*)d_out;

  const int N = in_sizes[0] / 128;
  const int E = in_sizes[1] / 2;
  const int NB = (N + 1023) / 1024;
  const int MB32 = (N + 31) / 32;
  const int SB4 = (E + 1023) / 1024;   // 4 edges/thread blocks
  const int PACKB = (2 * 272 * 128 + 64 * 128 + 255) / 256;

  char* p = (char*)d_ws;
  unsigned int* ylin    = (unsigned int*)p;   p += (size_t)N * 64 * 4;
  unsigned short* xsb   = (unsigned short*)p; p += (size_t)N * 128 * 2;
  unsigned short* hb    = (unsigned short*)p; p += (size_t)N * 128 * 2;
  unsigned short* asd_s = (unsigned short*)p; p += (size_t)N * 8 * 2;
  unsigned short* asd_d = (unsigned short*)p; p += (size_t)N * 8 * 2;
  unsigned short* wt0   = (unsigned short*)p; p += (size_t)272 * 128 * 2;
  unsigned short* wt1   = (unsigned short*)p; p += (size_t)272 * 128 * 2;
  unsigned short* wot   = (unsigned short*)p; p += (size_t)64 * 128 * 2;
  int* rowptr = (int*)p;                      p += (size_t)(N + 4) * 4;
  int* deg    = (int*)p;                      p += (size_t)N * 4;
  int* lex    = (int*)p;                      p += (size_t)N * 4;
  int* bsum   = (int*)p;                      p += (size_t)256 * 4;
  unsigned short* col  = (unsigned short*)p;  p += (size_t)E * 2;
  unsigned short* rank = (unsigned short*)p;  p += (size_t)E * 2;

  dim3 b256(256);

  hipMemsetAsync(deg, 0, (size_t)N * 4, stream);
  // pack all weights ∪ degree count + per-edge rank (one dispatch)
  k_init<<<PACKB + SB4, b256, 0, stream>>>(
      W_lin0, W_src0, W_dst0, att_s0, att_d0,
      W_lin1, W_src1, W_dst1, att_s1, att_d1,
      W_out, wt0, wt1, wot, ei, deg, rank, E, PACKB);
  k_scan_local<<<NB, b256, 0, stream>>>(deg, lex, bsum, N);
  k_scan_add<<<(N + 256) / 256, b256, 0, stream>>>(lex, bsum, rowptr, N, NB, E);

  // layer-0 GEMM ∪ atomic-free CSR scatter, Bresenham-interleaved
  k_gemm0_scatter<<<MB32 + SB4, b256, 0, stream>>>(
      x, wt0, b_lin0, b_cnv0, ylin, xsb, asd_s, asd_d, N, MB32,
      ei, rowptr, rank, col, E, MB32 + SB4);

  k_aggregate<<<(N + 3) / 4, b256, 0, stream>>>(
      ylin, (const unsigned int*)xsb, asd_s, asd_d, rowptr, col,
      (unsigned int*)hb, N);
  k_gemm_fused1<<<MB32, b256, 0, stream>>>(hb, wt1, b_lin1, b_cnv1,
                                           ylin, xsb, asd_s, asd_d, N);
  k_aggregate<<<(N + 3) / 4, b256, 0, stream>>>(
      ylin, (const unsigned int*)xsb, asd_s, asd_d, rowptr, col,
      (unsigned int*)hb, N);
  k_gemm_out<<<MB32, b256, 0, stream>>>(hb, wot, b_out, out, N);
}

// Round 16
// 153.245 us; speedup vs baseline: 1.4020x; 1.0199x over previous
//
#include <hip/hip_runtime.h>
#include <cstdint>
#include <cstddef>

#define NEG_SLOPE 0.2f

typedef __bf16 bf16x8 __attribute__((ext_vector_type(8)));
typedef float f32x4 __attribute__((ext_vector_type(4)));

static __device__ __forceinline__ unsigned short f2bf(float f) {
  unsigned int u = __float_as_uint(f);
  unsigned int r = (u + 0x7FFFu + ((u >> 16) & 1u)) >> 16;
  return (unsigned short)r;
}
static __device__ __forceinline__ float bf2f(unsigned short u) {
  return __uint_as_float(((unsigned int)u) << 16);
}
static __device__ __forceinline__ float pklo(unsigned int x) {
  return __uint_as_float(x << 16);
}
static __device__ __forceinline__ float pkhi(unsigned int x) {
  return __uint_as_float(x & 0xffff0000u);
}

// ---------------- CSR scan ----------------
__global__ __launch_bounds__(256) void k_scan_local(const int* __restrict__ deg,
                                                    int* __restrict__ lex,
                                                    int* __restrict__ bsum, int n) {
  __shared__ int ts[256];
  const int t = threadIdx.x;
  const int base = blockIdx.x * 1024 + t * 4;
  int4 d = {0, 0, 0, 0};
  if (base + 3 < n) d = *reinterpret_cast<const int4*>(&deg[base]);
  else {
    if (base + 0 < n) d.x = deg[base + 0];
    if (base + 1 < n) d.y = deg[base + 1];
    if (base + 2 < n) d.z = deg[base + 2];
  }
  int s = d.x + d.y + d.z + d.w;
  ts[t] = s;
  __syncthreads();
  for (int off = 1; off < 256; off <<= 1) {
    int y = (t >= off) ? ts[t - off] : 0;
    __syncthreads();
    ts[t] += y;
    __syncthreads();
  }
  int pre = ts[t] - s;
  int4 o;
  o.x = pre; o.y = pre + d.x; o.z = pre + d.x + d.y; o.w = pre + d.x + d.y + d.z;
  if (base + 3 < n) *reinterpret_cast<int4*>(&lex[base]) = o;
  else {
    if (base + 0 < n) lex[base + 0] = o.x;
    if (base + 1 < n) lex[base + 1] = o.y;
    if (base + 2 < n) lex[base + 2] = o.z;
  }
  if (t == 255) bsum[blockIdx.x] = ts[255];
}

// scan_add with embedded (redundant per-block) bsum exclusive scan.
__global__ __launch_bounds__(256) void k_scan_add(
    const int* __restrict__ lex, const int* __restrict__ bsum,
    int* __restrict__ rowptr, int n, int nb, int E) {
  __shared__ int ts[256];
  const int t = threadIdx.x;
  int v = (t < nb) ? bsum[t] : 0;
  ts[t] = v;
  __syncthreads();
  for (int off = 1; off < 256; off <<= 1) {
    int y = (t >= off) ? ts[t - off] : 0;
    __syncthreads();
    ts[t] += y;
    __syncthreads();
  }
  int excl = ts[t] - v;
  __syncthreads();
  ts[t] = excl;
  __syncthreads();
  int i = blockIdx.x * 256 + t;
  if (i < n) rowptr[i] = lex[i] + ts[i >> 10];
  if (i == n) rowptr[n] = E;
}

// ---------------- k_init: weight pack ∪ degree count + edge rank (4/thread) --
static __device__ __forceinline__ unsigned short pack_wt_elem(
    const float* __restrict__ Wl, const float* __restrict__ Ws,
    const float* __restrict__ Wd, const float* __restrict__ as_,
    const float* __restrict__ ad_, int t) {
  int j = t >> 7, k = t & 127;
  float val;
  if (j < 128) val = Wl[k * 128 + j];
  else if (j < 256) val = Ws[k * 128 + (j - 128)];
  else {
    int jj = j - 256;
    int h = jj & 7;
    const float* W = (jj < 8) ? Ws : Wd;
    const float* a = (jj < 8) ? as_ : ad_;
    float s = 0.f;
#pragma unroll
    for (int c = 0; c < 16; ++c) s += W[k * 128 + h * 16 + c] * a[h * 16 + c];
    val = s;
  }
  return f2bf(val);
}

__global__ void k_init(
    const float* __restrict__ Wl0, const float* __restrict__ Ws0, const float* __restrict__ Wd0,
    const float* __restrict__ as0, const float* __restrict__ ad0,
    const float* __restrict__ Wl1, const float* __restrict__ Ws1, const float* __restrict__ Wd1,
    const float* __restrict__ as1, const float* __restrict__ ad1,
    const float* __restrict__ Wo,
    unsigned short* __restrict__ wt0, unsigned short* __restrict__ wt1,
    unsigned short* __restrict__ wot,
    const int* __restrict__ ei, int* __restrict__ deg,
    unsigned short* __restrict__ rank, int E, int packBlocks) {
  const int SZ = 272 * 128;
  if ((int)blockIdx.x < packBlocks) {
    int t = blockIdx.x * 256 + threadIdx.x;
    if (t < SZ) {
      wt0[t] = pack_wt_elem(Wl0, Ws0, Wd0, as0, ad0, t);
    } else if (t < 2 * SZ) {
      wt1[t - SZ] = pack_wt_elem(Wl1, Ws1, Wd1, as1, ad1, t - SZ);
    } else if (t < 2 * SZ + 64 * 128) {
      int u = t - 2 * SZ;
      int nn = u >> 7, k = u & 127;
      wot[u] = f2bf(Wo[k * 64 + nn]);
    }
  } else {
    int e = ((blockIdx.x - packBlocks) * 256 + threadIdx.x) * 4;
    if (e + 3 < E) {
      int4 d4 = *reinterpret_cast<const int4*>(&ei[E + e]);
      ushort4 r4;
      r4.x = (unsigned short)atomicAdd(&deg[d4.x], 1);
      r4.y = (unsigned short)atomicAdd(&deg[d4.y], 1);
      r4.z = (unsigned short)atomicAdd(&deg[d4.z], 1);
      r4.w = (unsigned short)atomicAdd(&deg[d4.w], 1);
      *reinterpret_cast<ushort4*>(&rank[e]) = r4;
    } else {
      for (int q = 0; q < 4 && e + q < E; ++q)
        rank[e + q] = (unsigned short)atomicAdd(&deg[ei[E + e + q]], 1);
    }
  }
}

// ---- shared GEMM body: one 32-row tile, B-frags already in registers ----
template <typename TIN>
static __device__ __forceinline__ void gemm_tile_body(
    const TIN* __restrict__ X, const bf16x8 bfr[4][4], const bf16x8 bfr4[4],
    const float* __restrict__ bl, const float* __restrict__ bc,
    unsigned int* __restrict__ ylin_pk, unsigned short* __restrict__ xsb,
    unsigned short* __restrict__ asd_s, unsigned short* __restrict__ asd_d,
    int n, int row0, unsigned short (*xa)[136],
    int tid, int wave, int lane, int lr, int lg, int f0, bool w3) {
  if constexpr (sizeof(TIN) == 4) {
#pragma unroll
    for (int ii = 0; ii < 4; ++ii) {
      int c = tid + ii * 256;
      int r = c >> 5, kq = c & 31;
      float4 v = make_float4(0.f, 0.f, 0.f, 0.f);
      if (row0 + r < n)
        v = reinterpret_cast<const float4*>(X)[(size_t)(row0 + r) * 32 + kq];
      ushort4 o;
      o.x = f2bf(v.x); o.y = f2bf(v.y); o.z = f2bf(v.z); o.w = f2bf(v.w);
      *reinterpret_cast<ushort4*>(&xa[r][kq * 4]) = o;
    }
  } else {
#pragma unroll
    for (int ii = 0; ii < 2; ++ii) {
      int c = tid + ii * 256;
      int r = c >> 4, ko = c & 15;
      uint4 v = {0u, 0u, 0u, 0u};
      if (row0 + r < n)
        v = reinterpret_cast<const uint4*>(X)[(size_t)(row0 + r) * 16 + ko];
      *reinterpret_cast<uint4*>(&xa[r][ko * 8]) = v;
    }
  }
  __syncthreads();

  f32x4 acc[2][4];
  f32x4 acc4[2];
#pragma unroll
  for (int g = 0; g < 2; ++g) {
    acc4[g] = (f32x4){0.f, 0.f, 0.f, 0.f};
#pragma unroll
    for (int ff = 0; ff < 4; ++ff) acc[g][ff] = (f32x4){0.f, 0.f, 0.f, 0.f};
  }

#pragma unroll
  for (int s = 0; s < 4; ++s) {
    bf16x8 a0 = *reinterpret_cast<const bf16x8*>(&xa[lr][s * 32 + lg * 8]);
    bf16x8 a1 = *reinterpret_cast<const bf16x8*>(&xa[16 + lr][s * 32 + lg * 8]);
#pragma unroll
    for (int ff = 0; ff < 4; ++ff) {
      acc[0][ff] = __builtin_amdgcn_mfma_f32_16x16x32_bf16(a0, bfr[ff][s], acc[0][ff], 0, 0, 0);
      acc[1][ff] = __builtin_amdgcn_mfma_f32_16x16x32_bf16(a1, bfr[ff][s], acc[1][ff], 0, 0, 0);
    }
    if (w3) {
      acc4[0] = __builtin_amdgcn_mfma_f32_16x16x32_bf16(a0, bfr4[s], acc4[0], 0, 0, 0);
      acc4[1] = __builtin_amdgcn_mfma_f32_16x16x32_bf16(a1, bfr4[s], acc4[1], 0, 0, 0);
    }
  }

  if (f0 < 8) {
#pragma unroll
    for (int g = 0; g < 2; ++g)
#pragma unroll
      for (int ff = 0; ff < 4; ++ff) {
        int j = (f0 + ff) * 16 + lr;
        float blc = bl[j] + bc[j];
#pragma unroll
        for (int r = 0; r < 4; ++r) {
          int row = row0 + g * 16 + lg * 4 + r;
          float vb = acc[g][ff][r] + blc;
          float v2 = __shfl(vb, lane ^ 1);
          if (row < n && (lr & 1) == 0)
            ylin_pk[(size_t)row * 64 + (j >> 1)] =
                (unsigned int)f2bf(vb) | ((unsigned int)f2bf(v2) << 16);
        }
      }
  } else {
#pragma unroll
    for (int g = 0; g < 2; ++g)
#pragma unroll
      for (int ff = 0; ff < 4; ++ff) {
        int j = (f0 - 8 + ff) * 16 + lr;
#pragma unroll
        for (int r = 0; r < 4; ++r) {
          int row = row0 + g * 16 + lg * 4 + r;
          if (row < n) xsb[(size_t)row * 128 + j] = f2bf(acc[g][ff][r]);
        }
      }
    if (w3) {
#pragma unroll
      for (int g = 0; g < 2; ++g)
#pragma unroll
        for (int r = 0; r < 4; ++r) {
          int row = row0 + g * 16 + lg * 4 + r;
          if (row < n) {
            unsigned short v = f2bf(acc4[g][r]);
            if (lr < 8) asd_s[(size_t)row * 8 + lr] = v;
            else        asd_d[(size_t)row * 8 + (lr - 8)] = v;
          }
        }
    }
  }
}

// ---------------- k_gemm0_scatter: layer-0 GEMM (2 tiles/block) ∪ scatter ----
__global__ __launch_bounds__(256, 3) void k_gemm0_scatter(
    const float* __restrict__ X, const unsigned short* __restrict__ wt,
    const float* __restrict__ bl, const float* __restrict__ bc,
    unsigned int* __restrict__ ylin_pk, unsigned short* __restrict__ xsb,
    unsigned short* __restrict__ asd_s, unsigned short* __restrict__ asd_d,
    int n, int ntiles, int gemmBlocks,
    const int* __restrict__ ei, const int* __restrict__ rowptr,
    const unsigned short* __restrict__ rank,
    unsigned short* __restrict__ col, int E, int total) {
  __shared__ __align__(16) unsigned short xa[32][136];
  const int i = blockIdx.x;
  const int before = (int)(((long long)i * gemmBlocks) / total);
  const int after  = (int)(((long long)(i + 1) * gemmBlocks) / total);

  if (after == before) {           // ---- scatter block (no atomics, 4/thread) ----
    int e = ((i - after) * 256 + threadIdx.x) * 4;
    if (e + 3 < E) {
      int4 s4 = *reinterpret_cast<const int4*>(&ei[e]);
      int4 d4 = *reinterpret_cast<const int4*>(&ei[E + e]);
      ushort4 r4 = *reinterpret_cast<const ushort4*>(&rank[e]);
      int p0 = rowptr[d4.x] + (int)r4.x;
      int p1 = rowptr[d4.y] + (int)r4.y;
      int p2 = rowptr[d4.z] + (int)r4.z;
      int p3 = rowptr[d4.w] + (int)r4.w;
      col[p0] = (unsigned short)s4.x;
      col[p1] = (unsigned short)s4.y;
      col[p2] = (unsigned short)s4.z;
      col[p3] = (unsigned short)s4.w;
    } else {
      for (int q = 0; q < 4 && e + q < E; ++q) {
        int d = ei[E + e + q];
        col[rowptr[d] + (int)rank[e + q]] = (unsigned short)ei[e + q];
      }
    }
    return;
  }

  // ---- gemm block: tiles 2*before and 2*before+1, B-frags reused ----
  const int tid = threadIdx.x;
  const int wave = tid >> 6, lane = tid & 63;
  const int lr = lane & 15, lg = lane >> 4;
  const int f0 = wave * 4;
  const bool w3 = (wave == 3);

  bf16x8 bfr[4][4];
#pragma unroll
  for (int ff = 0; ff < 4; ++ff)
#pragma unroll
    for (int s = 0; s < 4; ++s)
      bfr[ff][s] = *reinterpret_cast<const bf16x8*>(
          &wt[(size_t)((f0 + ff) * 16 + lr) * 128 + s * 32 + lg * 8]);
  bf16x8 bfr4[4];
  if (w3) {
#pragma unroll
    for (int s = 0; s < 4; ++s)
      bfr4[s] = *reinterpret_cast<const bf16x8*>(
          &wt[(size_t)(256 + lr) * 128 + s * 32 + lg * 8]);
  }

#pragma unroll
  for (int t2 = 0; t2 < 2; ++t2) {
    int tile = before * 2 + t2;
    if (tile >= ntiles) break;        // uniform across block
    if (t2) __syncthreads();          // protect LDS reuse
    gemm_tile_body<float>(X, bfr, bfr4, bl, bc, ylin_pk, xsb, asd_s, asd_d,
                          n, tile * 32, xa, tid, wave, lane, lr, lg, f0, w3);
  }
}

// ---------------- layer-1 fused MFMA GEMM (bf16 input, 2 tiles/block) --------
__global__ __launch_bounds__(256, 3) void k_gemm_fused1(
    const unsigned short* __restrict__ X, const unsigned short* __restrict__ wt,
    const float* __restrict__ bl, const float* __restrict__ bc,
    unsigned int* __restrict__ ylin_pk, unsigned short* __restrict__ xsb,
    unsigned short* __restrict__ asd_s, unsigned short* __restrict__ asd_d,
    int n, int ntiles) {
  __shared__ __align__(16) unsigned short xa[32][136];
  const int tid = threadIdx.x;
  const int wave = tid >> 6, lane = tid & 63;
  const int lr = lane & 15, lg = lane >> 4;
  const int f0 = wave * 4;
  const bool w3 = (wave == 3);

  bf16x8 bfr[4][4];
#pragma unroll
  for (int ff = 0; ff < 4; ++ff)
#pragma unroll
    for (int s = 0; s < 4; ++s)
      bfr[ff][s] = *reinterpret_cast<const bf16x8*>(
          &wt[(size_t)((f0 + ff) * 16 + lr) * 128 + s * 32 + lg * 8]);
  bf16x8 bfr4[4];
  if (w3) {
#pragma unroll
    for (int s = 0; s < 4; ++s)
      bfr4[s] = *reinterpret_cast<const bf16x8*>(
          &wt[(size_t)(256 + lr) * 128 + s * 32 + lg * 8]);
  }

#pragma unroll
  for (int t2 = 0; t2 < 2; ++t2) {
    int tile = blockIdx.x * 2 + t2;
    if (tile >= ntiles) break;
    if (t2) __syncthreads();
    gemm_tile_body<unsigned short>(X, bfr, bfr4, bl, bc, ylin_pk, xsb,
                                   asd_s, asd_d, n, tile * 32, xa,
                                   tid, wave, lane, lr, lg, f0, w3);
  }
}

// ---------------- final GEMM: out[N,64] = h@W_out + b (2 tiles/block) --------
__global__ __launch_bounds__(256, 3) void k_gemm_out(
    const unsigned short* __restrict__ X, const unsigned short* __restrict__ wot,
    const float* __restrict__ bias, float* __restrict__ out, int n, int ntiles) {
  __shared__ __align__(16) unsigned short xa[32][136];
  const int tid = threadIdx.x;
  const int wave = tid >> 6, lane = tid & 63;
  const int lr = lane & 15, lg = lane >> 4;

  bf16x8 bo[4];
#pragma unroll
  for (int s = 0; s < 4; ++s)
    bo[s] = *reinterpret_cast<const bf16x8*>(
        &wot[(size_t)(wave * 16 + lr) * 128 + s * 32 + lg * 8]);
  float bv = bias[wave * 16 + lr];

#pragma unroll
  for (int t2 = 0; t2 < 2; ++t2) {
    int tile = blockIdx.x * 2 + t2;
    if (tile >= ntiles) break;
    if (t2) __syncthreads();
    const int row0 = tile * 32;
#pragma unroll
    for (int i = 0; i < 2; ++i) {
      int c = tid + i * 256;
      int r = c >> 4, ko = c & 15;
      uint4 v = {0u, 0u, 0u, 0u};
      if (row0 + r < n)
        v = reinterpret_cast<const uint4*>(X)[(size_t)(row0 + r) * 16 + ko];
      *reinterpret_cast<uint4*>(&xa[r][ko * 8]) = v;
    }
    __syncthreads();

    f32x4 acc[2];
    acc[0] = (f32x4){0.f, 0.f, 0.f, 0.f};
    acc[1] = (f32x4){0.f, 0.f, 0.f, 0.f};
#pragma unroll
    for (int s = 0; s < 4; ++s) {
      bf16x8 a0 = *reinterpret_cast<const bf16x8*>(&xa[lr][s * 32 + lg * 8]);
      bf16x8 a1 = *reinterpret_cast<const bf16x8*>(&xa[16 + lr][s * 32 + lg * 8]);
      acc[0] = __builtin_amdgcn_mfma_f32_16x16x32_bf16(a0, bo[s], acc[0], 0, 0, 0);
      acc[1] = __builtin_amdgcn_mfma_f32_16x16x32_bf16(a1, bo[s], acc[1], 0, 0, 0);
    }
#pragma unroll
    for (int g = 0; g < 2; ++g)
#pragma unroll
      for (int r = 0; r < 4; ++r) {
        int row = row0 + g * 16 + lg * 4 + r;
        if (row < n) out[(size_t)row * 64 + wave * 16 + lr] = acc[g][r] + bv;
      }
  }
}

// ---------------- fused segment softmax + aggregation + node update ----------
// One wave per dst node. 16-edge software-pipelined chunks; branchless padding.
__global__ __launch_bounds__(256) void k_aggregate(
    const unsigned int* __restrict__ ylin_pk, const unsigned int* __restrict__ xsp,
    const unsigned short* __restrict__ asd_s, const unsigned short* __restrict__ asd_d,
    const int* __restrict__ rowptr, const unsigned short* __restrict__ col,
    unsigned int* __restrict__ hout_pk, int n) {
  int node = (blockIdx.x * blockDim.x + threadIdx.x) >> 6;
  if (node >= n) return;
  const int lane = threadIdx.x & 63;
  const int el = lane >> 3;
  const int hh = lane & 7;
  const int hb4 = (lane >> 3) << 2;
  const int beg = rowptr[node], end = rowptr[node + 1];

  const float ad_hh = bf2f(asd_d[(size_t)node * 8 + hh]);
  unsigned int y = __builtin_nontemporal_load(&ylin_pk[(size_t)node * 64 + lane]);

  float dsum = 0.f, acc0 = 0.f, acc1 = 0.f;
  int ebase = beg;
  for (; ebase + 8 < end; ebase += 16) {
    int eA = ebase + el;
    int eB = ebase + 8 + el;
    bool vB = eB < end;
    int esB = vB ? eB : (end - 1);
    int srcA = (int)col[eA];          // col reused across layers -> keep cached
    int srcB = (int)col[esB];
    float svA = bf2f(asd_s[(size_t)srcA * 8 + hh]) + ad_hh;
    float svB = bf2f(asd_s[(size_t)srcB * 8 + hh]) + ad_hh;
    svA = fmaxf(svA, NEG_SLOPE * svA);
    svB = fmaxf(svB, NEG_SLOPE * svB);
    float peA = __expf(svA);
    float peB = vB ? __expf(svB) : 0.f;
#pragma unroll
    for (int q = 0; q < 8; ++q) {
      float pq = __uint_as_float(__builtin_amdgcn_ds_bpermute(
          q * 32 + hb4, __float_as_uint(peA)));
      int sq = __builtin_amdgcn_readlane(srcA, q * 8);
      unsigned int xv = xsp[(size_t)sq * 64 + lane];
      dsum += pq;
      acc0 += pq * pklo(xv);
      acc1 += pq * pkhi(xv);
    }
#pragma unroll
    for (int q = 0; q < 8; ++q) {
      float pq = __uint_as_float(__builtin_amdgcn_ds_bpermute(
          q * 32 + hb4, __float_as_uint(peB)));
      int sq = __builtin_amdgcn_readlane(srcB, q * 8);
      unsigned int xv = xsp[(size_t)sq * 64 + lane];
      dsum += pq;
      acc0 += pq * pklo(xv);
      acc1 += pq * pkhi(xv);
    }
  }
  for (; ebase < end; ebase += 8) {
    int e1 = ebase + el;
    bool valid = e1 < end;
    int esafe = valid ? e1 : (end - 1);
    int srcp = (int)col[esafe];
    float sv = bf2f(asd_s[(size_t)srcp * 8 + hh]) + ad_hh;
    sv = fmaxf(sv, NEG_SLOPE * sv);
    float pe = valid ? __expf(sv) : 0.f;
#pragma unroll
    for (int q = 0; q < 8; ++q) {
      float pq = __uint_as_float(__builtin_amdgcn_ds_bpermute(
          q * 32 + hb4, __float_as_uint(pe)));
      int sq = __builtin_amdgcn_readlane(srcp, q * 8);
      unsigned int xv = xsp[(size_t)sq * 64 + lane];
      dsum += pq;
      acc0 += pq * pklo(xv);
      acc1 += pq * pkhi(xv);
    }
  }
  float inv = 1.f / (dsum + 1e-16f);
  float l0 = pklo(y) + acc0 * inv;
  float l1 = pkhi(y) + acc1 * inv;
  l0 = l0 > 0.f ? l0 : __expf(l0) - 1.f;
  l1 = l1 > 0.f ? l1 : __expf(l1) - 1.f;
  hout_pk[(size_t)node * 64 + lane] =
      (unsigned int)f2bf(l0) | ((unsigned int)f2bf(l1) << 16);
}

// ---------------- launch ----------------
extern "C" void kernel_launch(void* const* d_in, const int* in_sizes, int n_in,
                              void* d_out, int out_size, void* d_ws, size_t ws_size,
                              hipStream_t stream) {
  const float* x      = (const float*)d_in[0];
  const int*   ei     = (const int*)d_in[1];
  const float* W_lin0 = (const float*)d_in[2];
  const float* b_lin0 = (const float*)d_in[3];
  const float* W_src0 = (const float*)d_in[4];
  const float* W_dst0 = (const float*)d_in[5];
  const float* att_s0 = (const float*)d_in[6];
  const float* att_d0 = (const float*)d_in[7];
  const float* b_cnv0 = (const float*)d_in[8];
  const float* W_lin1 = (const float*)d_in[9];
  const float* b_lin1 = (const float*)d_in[10];
  const float* W_src1 = (const float*)d_in[11];
  const float* W_dst1 = (const float*)d_in[12];
  const float* att_s1 = (const float*)d_in[13];
  const float* att_d1 = (const float*)d_in[14];
  const float* b_cnv1 = (const float*)d_in[15];
  const float* W_out  = (const float*)d_in[16];
  const float* b_out  = (const float*)d_in[17];
  float* out = (float*)d_out;

  const int N = in_sizes[0] / 128;
  const int E = in_sizes[1] / 2;
  const int NB = (N + 1023) / 1024;
  const int MB32 = (N + 31) / 32;
  const int MBH = (MB32 + 1) / 2;      // 2 tiles per GEMM block
  const int SB4 = (E + 1023) / 1024;
  const int PACKB = (2 * 272 * 128 + 64 * 128 + 255) / 256;

  char* p = (char*)d_ws;
  unsigned int* ylin    = (unsigned int*)p;   p += (size_t)N * 64 * 4;
  unsigned short* xsb   = (unsigned short*)p; p += (size_t)N * 128 * 2;
  unsigned short* hb    = (unsigned short*)p; p += (size_t)N * 128 * 2;
  unsigned short* asd_s = (unsigned short*)p; p += (size_t)N * 8 * 2;
  unsigned short* asd_d = (unsigned short*)p; p += (size_t)N * 8 * 2;
  unsigned short* wt0   = (unsigned short*)p; p += (size_t)272 * 128 * 2;
  unsigned short* wt1   = (unsigned short*)p; p += (size_t)272 * 128 * 2;
  unsigned short* wot   = (unsigned short*)p; p += (size_t)64 * 128 * 2;
  int* rowptr = (int*)p;                      p += (size_t)(N + 4) * 4;
  int* deg    = (int*)p;                      p += (size_t)N * 4;
  int* lex    = (int*)p;                      p += (size_t)N * 4;
  int* bsum   = (int*)p;                      p += (size_t)256 * 4;
  unsigned short* col  = (unsigned short*)p;  p += (size_t)E * 2;
  unsigned short* rank = (unsigned short*)p;  p += (size_t)E * 2;

  dim3 b256(256);

  hipMemsetAsync(deg, 0, (size_t)N * 4, stream);
  k_init<<<PACKB + SB4, b256, 0, stream>>>(
      W_lin0, W_src0, W_dst0, att_s0, att_d0,
      W_lin1, W_src1, W_dst1, att_s1, att_d1,
      W_out, wt0, wt1, wot, ei, deg, rank, E, PACKB);
  k_scan_local<<<NB, b256, 0, stream>>>(deg, lex, bsum, N);
  k_scan_add<<<(N + 256) / 256, b256, 0, stream>>>(lex, bsum, rowptr, N, NB, E);

  // layer-0 GEMM (2 tiles/block) ∪ atomic-free CSR scatter, interleaved
  k_gemm0_scatter<<<MBH + SB4, b256, 0, stream>>>(
      x, wt0, b_lin0, b_cnv0, ylin, xsb, asd_s, asd_d, N, MB32, MBH,
      ei, rowptr, rank, col, E, MBH + SB4);

  k_aggregate<<<(N + 3) / 4, b256, 0, stream>>>(
      ylin, (const unsigned int*)xsb, asd_s, asd_d, rowptr, col,
      (unsigned int*)hb, N);
  k_gemm_fused1<<<MBH, b256, 0, stream>>>(hb, wt1, b_lin1, b_cnv1,
                                          ylin, xsb, asd_s, asd_d, N, MB32);
  k_aggregate<<<(N + 3) / 4, b256, 0, stream>>>(
      ylin, (const unsigned int*)xsb, asd_s, asd_d, rowptr, col,
      (unsigned int*)hb, N);
  k_gemm_out<<<MBH, b256, 0, stream>>>(hb, wot, b_out, out, N, MB32);
}